// Round 8
// baseline (2997.206 us; speedup 1.0000x reference)
//
#include <hip/hip_runtime.h>

typedef unsigned short u16;
typedef unsigned int   u32;
typedef __attribute__((ext_vector_type(4))) float  f32x4;
typedef __attribute__((ext_vector_type(8))) __bf16 bf16x8;
typedef __attribute__((ext_vector_type(8))) short  s16x8;
typedef __attribute__((ext_vector_type(4))) unsigned short u16x4;

#define DEVFN __device__ __forceinline__

DEVFN float bf2f(u16 u) {
    u32 v = ((u32)u) << 16;
    return __builtin_bit_cast(float, v);
}
DEVFN u16 f2bf(float f) {   // round-to-nearest-even
    u32 u = __builtin_bit_cast(u32, f);
    u32 r = u + 0x7FFFu + ((u >> 16) & 1u);
    return (u16)(r >> 16);
}

// async global->LDS, 16B per lane. LDS dest must be linear in lane order.
DEVFN void gload16(const void* g, void* l) {
    __builtin_amdgcn_global_load_lds(
        (const __attribute__((address_space(1))) void*)g,
        (__attribute__((address_space(3))) void*)l, 16, 0, 0);
}

// ---------------- embedding
__global__ __launch_bounds__(256) void embed_k(const int* __restrict__ idx,
                                               const float* __restrict__ tok,
                                               const float* __restrict__ pos,
                                               float* __restrict__ x)
{
    int i   = blockIdx.x * 256 + threadIdx.x;
    int row = i >> 8;
    int c   = (i & 255) << 2;
    int t   = row & 1023;
    int tk  = idx[row];
    float4 a = *(const float4*)&tok[(size_t)tk * 1024 + c];
    float4 p = *(const float4*)&pos[(size_t)t * 1024 + c];
    float4 r; r.x = a.x + p.x; r.y = a.y + p.y; r.z = a.z + p.z; r.w = a.w + p.w;
    *(float4*)&x[(size_t)row * 1024 + c] = r;
}

// ---------------- fp32 [K,N] -> bf16 [N,K] transpose (single matrix; head)
__global__ __launch_bounds__(256) void transpose_k(const float* __restrict__ W,
                                                   u16* __restrict__ Wt, int K, int N)
{
    __shared__ float tile[32][33];
    int n0 = blockIdx.x * 32, k0 = blockIdx.y * 32;
    int xx = threadIdx.x, ty = threadIdx.y;      // block (32,8)
#pragma unroll
    for (int yy = 0; yy < 4; ++yy) {
        int y = ty + yy * 8;
        tile[y][xx] = W[(size_t)(k0 + y) * N + n0 + xx];
    }
    __syncthreads();
#pragma unroll
    for (int yy = 0; yy < 4; ++yy) {
        int y = ty + yy * 8;
        Wt[(size_t)(n0 + y) * K + k0 + xx] = f2bf(tile[xx][y]);
    }
}

// ---------------- fused per-layer weight transpose: Wq/Wk/Wv/Wo/W1/W2 in ONE launch
__global__ __launch_bounds__(256) void transpose_all_k(
    const float* __restrict__ Wq, const float* __restrict__ Wk,
    const float* __restrict__ Wv, const float* __restrict__ Wo,
    const float* __restrict__ W1, const float* __restrict__ W2,
    u16* __restrict__ qkvT, u16* __restrict__ woT,
    u16* __restrict__ w1T, u16* __restrict__ w2T)
{
    __shared__ float tile[32][33];
    const int id = blockIdx.x;
    const float* W; u16* Wt; int K, N, bx, by;
    if (id < 3072) {
        const int m = id >> 10, t2 = id & 1023;
        W = (m == 0) ? Wq : (m == 1) ? Wk : Wv;
        Wt = qkvT + (size_t)m * 1024 * 1024;
        K = 1024; N = 1024; bx = t2 & 31; by = t2 >> 5;
    } else if (id < 4096) {
        const int t2 = id - 3072;
        W = Wo; Wt = woT; K = 1024; N = 1024; bx = t2 & 31; by = t2 >> 5;
    } else if (id < 8192) {
        const int t2 = id - 4096;
        W = W1; Wt = w1T; K = 1024; N = 4096; bx = t2 & 127; by = t2 >> 7;
    } else {
        const int t2 = id - 8192;
        W = W2; Wt = w2T; K = 4096; N = 1024; bx = t2 & 31; by = t2 >> 5;
    }
    const int n0 = bx * 32, k0 = by * 32;
    const int xx = threadIdx.x, ty = threadIdx.y;    // block (32,8)
#pragma unroll
    for (int yy = 0; yy < 4; ++yy) {
        const int y = ty + yy * 8;
        tile[y][xx] = W[(size_t)(k0 + y) * N + n0 + xx];
    }
    __syncthreads();
#pragma unroll
    for (int yy = 0; yy < 4; ++yy) {
        const int y = ty + yy * 8;
        Wt[(size_t)(n0 + y) * K + k0 + xx] = f2bf(tile[xx][y]);
    }
}

// ---------------- LayerNorm: fp32 in -> bf16 out, C=1024, one block per row
__global__ __launch_bounds__(256) void ln_k(const float* __restrict__ x,
                                            const float* __restrict__ g,
                                            const float* __restrict__ b,
                                            u16* __restrict__ out)
{
    const int row = blockIdx.x, tid = threadIdx.x;
    const float4 v = *(const float4*)&x[(size_t)row * 1024 + tid * 4];
    __shared__ float red[8];
    float s = v.x + v.y + v.z + v.w;
#pragma unroll
    for (int off = 32; off > 0; off >>= 1) s += __shfl_down(s, off);
    const int lane = tid & 63, wv = tid >> 6;
    if (lane == 0) red[wv] = s;
    __syncthreads();
    const float mu = (red[0] + red[1] + red[2] + red[3]) * (1.0f / 1024.0f);
    const float dx = v.x - mu, dy = v.y - mu, dz = v.z - mu, dw = v.w - mu;
    float s2 = dx * dx + dy * dy + dz * dz + dw * dw;
#pragma unroll
    for (int off = 32; off > 0; off >>= 1) s2 += __shfl_down(s2, off);
    if (lane == 0) red[4 + wv] = s2;
    __syncthreads();
    const float var = (red[4] + red[5] + red[6] + red[7]) * (1.0f / 1024.0f);
    const float rs  = rsqrtf(var + 1e-5f);
    const float4 gv = *(const float4*)&g[tid * 4];
    const float4 bv = *(const float4*)&b[tid * 4];
    u16x4 o;
    o.x = f2bf(dx * rs * gv.x + bv.x);
    o.y = f2bf(dy * rs * gv.y + bv.y);
    o.z = f2bf(dz * rs * gv.z + bv.z);
    o.w = f2bf(dw * rs * gv.w + bv.w);
    *(u16x4*)&out[(size_t)row * 1024 + tid * 4] = o;
}

// ---------------- bf16 MFMA GEMM (proven 128x128, kept for wo/ffn2/head)
template <int MODE>
__global__ __launch_bounds__(256) void gemm_bt(const u16* __restrict__ A,
                                               const u16* __restrict__ Bt,
                                               const float* __restrict__ bias,
                                               float* __restrict__ RES,
                                               u16* __restrict__ Ob,
                                               float* __restrict__ Of,
                                               int N, int K, int ntx)
{
    __shared__ __align__(16) u16 As[2][128 * 32];
    __shared__ __align__(16) u16 Bs[2][128 * 32];
    const int tid  = threadIdx.x;
    const int lane = tid & 63, wave = tid >> 6;
    const int wr = wave >> 1, wc = wave & 1;
    const int l15 = lane & 15, l4 = lane >> 4;

    const int nwg = (int)gridDim.x;
    const int bid = (int)blockIdx.x;
    const int swz = (bid & 7) * (nwg >> 3) + (bid >> 3);
    const int n0 = (swz % ntx) * 128, m0 = (swz / ntx) * 128;

    f32x4 acc[4][4];
    const f32x4 zz = {0.f, 0.f, 0.f, 0.f};
#pragma unroll
    for (int i = 0; i < 4; ++i)
#pragma unroll
        for (int j = 0; j < 4; ++j) acc[i][j] = zz;

    const int r0 = tid >> 2, q0q = (tid & 3) * 8;
    const int r1 = (tid + 256) >> 2, q1q = ((tid + 256) & 3) * 8;
    const u16* Arow0 = &A [(size_t)(m0 + r0) * K + q0q];
    const u16* Brow0 = &Bt[(size_t)(n0 + r0) * K + q0q];
    const u16* Arow1 = &A [(size_t)(m0 + r1) * K + q1q];
    const u16* Brow1 = &Bt[(size_t)(n0 + r1) * K + q1q];

    gload16(Arow0, &As[0][tid * 8]);
    gload16(Brow0, &Bs[0][tid * 8]);
    gload16(Arow1, &As[0][(tid + 256) * 8]);
    gload16(Brow1, &Bs[0][(tid + 256) * 8]);
    __syncthreads();

    const int S = K >> 5;
    int cur = 0;
    for (int s = 0; s < S; ++s) {
        if (s + 1 < S) {
            const int kn = (s + 1) << 5;
            gload16(Arow0 + kn, &As[cur ^ 1][tid * 8]);
            gload16(Brow0 + kn, &Bs[cur ^ 1][tid * 8]);
            gload16(Arow1 + kn, &As[cur ^ 1][(tid + 256) * 8]);
            gload16(Brow1 + kn, &Bs[cur ^ 1][(tid + 256) * 8]);
        }
        s16x8 af[4], bw[4];
#pragma unroll
        for (int i = 0; i < 4; ++i)
            af[i] = *(const s16x8*)&As[cur][(wr * 64 + i * 16 + l15) * 32 + l4 * 8];
#pragma unroll
        for (int j = 0; j < 4; ++j)
            bw[j] = *(const s16x8*)&Bs[cur][(wc * 64 + j * 16 + l15) * 32 + l4 * 8];
#pragma unroll
        for (int i = 0; i < 4; ++i)
#pragma unroll
            for (int j = 0; j < 4; ++j)
                acc[i][j] = __builtin_amdgcn_mfma_f32_16x16x32_bf16(
                    __builtin_bit_cast(bf16x8, af[i]),
                    __builtin_bit_cast(bf16x8, bw[j]), acc[i][j], 0, 0, 0);
        __syncthreads();
        cur ^= 1;
    }

#pragma unroll
    for (int i = 0; i < 4; ++i) {
        const int rb = m0 + wr * 64 + i * 16 + l4 * 4;
#pragma unroll
        for (int j = 0; j < 4; ++j) {
            const int col = n0 + wc * 64 + j * 16 + l15;
            const float bval = (MODE == 0) ? 0.0f : bias[col];
#pragma unroll
            for (int r = 0; r < 4; ++r) {
                const size_t o = (size_t)(rb + r) * N + col;
                const float v = acc[i][j][r];
                if (MODE == 0)      Ob[o] = f2bf(v);
                else if (MODE == 1) RES[o] += v + bval;
                else if (MODE == 2) Ob[o] = f2bf(fmaxf(v + bval, 0.0f));
                else                Of[o] = v + bval;
            }
        }
    }
}

// ---------------- 8-phase 256x256 GEMM (derived-waits port of T2+T3+T4+T5)
// BK=64, 512 thr = 8 waves (2M x 4N per quadrant). LDS 128 KB: per buf, A/B each
// 2 halves of [128][64] bf16, row-XOR swizzled (chunk ^= row&7). Per K-tile: 4
// phases {stage 1 half-tile; vmcnt(6); barrier; ds_read frags; setprio MFMA; barrier}.
// Stage order A0,B0,A1,B1; compute order (A0B0)(A1B0)(A1B1)(A0B1). Last tile
// drains vmcnt 4->2->0. MODE 0: bf16 out; MODE 2: relu(acc+bias) bf16 out.
template <int MODE>
__global__ __launch_bounds__(512, 1) void gemm8p(const u16* __restrict__ A,
                                                 const u16* __restrict__ Bt,
                                                 const float* __restrict__ bias,
                                                 u16* __restrict__ Ob,
                                                 int N, int K, int ntx)
{
    __shared__ __align__(16) u16 LA[2][2][128 * 64];
    __shared__ __align__(16) u16 LB[2][2][128 * 64];
    const int tid = threadIdx.x;
    const int lane = tid & 63, wid = tid >> 6;
    const int l15 = lane & 15, l4 = lane >> 4;
    const int wm = wid >> 2, wn = wid & 3;          // 2x4 wave grid in a quadrant

    const int nwg = (int)gridDim.x;
    const int bid = (int)blockIdx.x;
    const int swz = (bid & 7) * (nwg >> 3) + (bid >> 3);
    const int n0 = (swz % ntx) * 256, m0 = (swz / ntx) * 256;

    f32x4 acc[4][4][2];                              // [quad mh*2+nh][mf][nf]
    const f32x4 zz = {0.f, 0.f, 0.f, 0.f};
#pragma unroll
    for (int q = 0; q < 4; ++q)
#pragma unroll
        for (int i = 0; i < 4; ++i)
#pragma unroll
            for (int j = 0; j < 2; ++j) acc[q][i][j] = zz;

    // staging geometry: half-tile = 128 rows x 64 k = 1024 chunks(16B); 2 rounds.
    // physical chunk c -> row c>>3, col-chunk (c&7); source logical col = (c&7)^(row&7)
    const int c0 = tid,       sr0 = c0 >> 3, sl0 = ((c0 & 7) ^ (sr0 & 7)) * 8;
    const int c1 = 512 + tid, sr1 = c1 >> 3, sl1 = ((c1 & 7) ^ (sr1 & 7)) * 8;
    const u16* A0p = &A [(size_t)(m0 + sr0) * K + sl0];
    const u16* A1p = &A [(size_t)(m0 + sr1) * K + sl1];
    const u16* B0p = &Bt[(size_t)(n0 + sr0) * K + sl0];
    const u16* B1p = &Bt[(size_t)(n0 + sr1) * K + sl1];
    const size_t hstep = (size_t)128 * K;            // half -> +128 rows

#define STAGE_A(bufv, mh, kt) \
    gload16(A0p + (size_t)(mh) * hstep + (kt) * 64, &LA[bufv][mh][c0 * 8]); \
    gload16(A1p + (size_t)(mh) * hstep + (kt) * 64, &LA[bufv][mh][c1 * 8]);
#define STAGE_B(bufv, nh, kt) \
    gload16(B0p + (size_t)(nh) * hstep + (kt) * 64, &LB[bufv][nh][c0 * 8]); \
    gload16(B1p + (size_t)(nh) * hstep + (kt) * 64, &LB[bufv][nh][c1 * 8]);

    const int swr = (l15 & 7) << 4;                  // read-side XOR (row&7)<<4
#define COMPUTE(bufv, mh, nh) { \
    const char* Ab = (const char*)&LA[bufv][mh][0]; \
    const char* Bb = (const char*)&LB[bufv][nh][0]; \
    s16x8 af_[4][2], bf_[2][2]; \
    _Pragma("unroll") \
    for (int mf = 0; mf < 4; ++mf) { \
        const int row = wm * 64 + mf * 16 + l15; \
        _Pragma("unroll") \
        for (int ks = 0; ks < 2; ++ks) \
            af_[mf][ks] = *(const s16x8*)(Ab + row * 128 + ((ks * 64 + l4 * 16) ^ swr)); \
    } \
    _Pragma("unroll") \
    for (int nf = 0; nf < 2; ++nf) { \
        const int row = wn * 32 + nf * 16 + l15; \
        _Pragma("unroll") \
        for (int ks = 0; ks < 2; ++ks) \
            bf_[nf][ks] = *(const s16x8*)(Bb + row * 128 + ((ks * 64 + l4 * 16) ^ swr)); \
    } \
    __builtin_amdgcn_s_setprio(1); \
    _Pragma("unroll") \
    for (int mf = 0; mf < 4; ++mf) \
        _Pragma("unroll") \
        for (int nf = 0; nf < 2; ++nf) \
            _Pragma("unroll") \
            for (int ks = 0; ks < 2; ++ks) \
                acc[(mh) * 2 + (nh)][mf][nf] = __builtin_amdgcn_mfma_f32_16x16x32_bf16( \
                    __builtin_bit_cast(bf16x8, af_[mf][ks]), \
                    __builtin_bit_cast(bf16x8, bf_[nf][ks]), acc[(mh) * 2 + (nh)][mf][nf], 0, 0, 0); \
    __builtin_amdgcn_s_setprio(0); }

#define WAITV(n) asm volatile("s_waitcnt vmcnt(" #n ")" ::: "memory")
#define BAR()    __builtin_amdgcn_s_barrier()

    const int NT = K >> 6;
    // prologue: stage K-tile 0 (A0,B0,A1,B1)
    STAGE_A(0, 0, 0); STAGE_B(0, 0, 0); STAGE_A(0, 1, 0); STAGE_B(0, 1, 0);

    int buf = 0;
    for (int t = 0; t < NT - 1; ++t) {
        const int kt1 = t + 1;
        const int nb = buf ^ 1;
        // phase 0: needs A0_t,B0_t
        STAGE_A(nb, 0, kt1);
        WAITV(6); BAR();
        COMPUTE(buf, 0, 0);
        BAR();
        // phase 1: needs A1_t
        STAGE_B(nb, 0, kt1);
        WAITV(6); BAR();
        COMPUTE(buf, 1, 0);
        BAR();
        // phase 2: needs B1_t
        STAGE_A(nb, 1, kt1);
        WAITV(6); BAR();
        COMPUTE(buf, 1, 1);
        BAR();
        // phase 3: all landed
        STAGE_B(nb, 1, kt1);
        COMPUTE(buf, 0, 1);
        BAR();
        buf = nb;
    }
    // last tile: drain 4 -> 2 -> 0
    WAITV(4); BAR();
    COMPUTE(buf, 0, 0);
    BAR();
    WAITV(2); BAR();
    COMPUTE(buf, 1, 0);
    BAR();
    WAITV(0); BAR();
    COMPUTE(buf, 1, 1);
    BAR();
    COMPUTE(buf, 0, 1);

    // epilogue; C/D layout: col = lane&15, row = (lane>>4)*4 + reg
#pragma unroll
    for (int mh = 0; mh < 2; ++mh)
#pragma unroll
        for (int nh = 0; nh < 2; ++nh)
#pragma unroll
            for (int mf = 0; mf < 4; ++mf) {
                const int rb = m0 + mh * 128 + wm * 64 + mf * 16 + l4 * 4;
#pragma unroll
                for (int nf = 0; nf < 2; ++nf) {
                    const int col = n0 + nh * 128 + wn * 32 + nf * 16 + l15;
                    const float bval = (MODE == 0) ? 0.0f : bias[col];
#pragma unroll
                    for (int r = 0; r < 4; ++r) {
                        const size_t o = (size_t)(rb + r) * N + col;
                        const float v = acc[mh * 2 + nh][mf][nf][r];
                        if (MODE == 0) Ob[o] = f2bf(v);
                        else           Ob[o] = f2bf(fmaxf(v + bval, 0.0f));
                    }
                }
            }
#undef STAGE_A
#undef STAGE_B
#undef COMPUTE
#undef WAITV
#undef BAR
}

// ---------------- MFMA flash attention v4 (unchanged from round 7)
__global__ __launch_bounds__(256) void attn_mfma_k(const u16* __restrict__ QKV,
                                                   u16* __restrict__ Og)
{
    const int qt  = (int)(gridDim.x - 1 - blockIdx.x);   // heavy blocks first
    const int bh  = blockIdx.y;
    const int b   = bh >> 4, h = bh & 15;
    const int tid = threadIdx.x;
    const int wq  = tid >> 6, lane = tid & 63;
    const int l15 = lane & 15, l4 = lane >> 4;

    __shared__ __align__(16) u16 Ks[64 * 64];    // K rows, LINEAR + chunk XOR swizzle
    __shared__ __align__(16) u16 Vt[64][72];     // V^T rows d; u32 kv-pairs, rotated cols
    __shared__ __align__(16) u16 Ps[4][16][68];  // per-wave P
    u32* VtW = (u32*)&Vt[0][0];                  // row stride 36 u32

    const int qrow0 = qt * 128 + wq * 32;

    const u16* Qbase = QKV + (size_t)b * 1024 * 3072 + h * 64;
    const u16* Kbase = Qbase + 1024;
    const u16* Vbase = Qbase + 2048;

    s16x8 aQ[2][2];
#pragma unroll
    for (int qi = 0; qi < 2; ++qi) {
        const u16* qsrc = Qbase + (size_t)(qrow0 + qi * 16 + l15) * 3072;
        aQ[qi][0] = *(const s16x8*)(qsrc + l4 * 8);
        aQ[qi][1] = *(const s16x8*)(qsrc + 32 + l4 * 8);
    }

    f32x4 O[2][4];
    const f32x4 zz = {0.f, 0.f, 0.f, 0.f};
    float mrow[2][4], lrow[2][4];
#pragma unroll
    for (int qi = 0; qi < 2; ++qi) {
#pragma unroll
        for (int dj = 0; dj < 4; ++dj) O[qi][dj] = zz;
#pragma unroll
        for (int r = 0; r < 4; ++r) { mrow[qi][r] = -3.0e38f; lrow[qi][r] = 0.f; }
    }

    const int cw0 = tid, cw1 = 256 + tid;
    const int kr0 = cw0 >> 3, kc0 = ((cw0 & 7) ^ (kr0 & 7)) * 8;
    const int kr1 = cw1 >> 3, kc1 = ((cw1 & 7) ^ (kr1 & 7)) * 8;
    const int vp  = tid >> 3;
    const int vdg = tid & 7;
    const int vc  = (vp + 4 * vdg) & 31;

    const int ntiles = 2 * qt + 2;
    for (int t = 0; t < ntiles; ++t) {
        const int kv0 = t * 64;
        __syncthreads();
        gload16(Kbase + (size_t)(kv0 + kr0) * 3072 + kc0, &Ks[cw0 * 8]);
        gload16(Kbase + (size_t)(kv0 + kr1) * 3072 + kc1, &Ks[cw1 * 8]);
        {
            const u16* vb0 = Vbase + (size_t)(kv0 + 2 * vp) * 3072 + vdg * 8;
            s16x8 v0 = *(const s16x8*)vb0;
            s16x8 v1 = *(const s16x8*)(vb0 + 3072);
#pragma unroll
            for (int e = 0; e < 8; ++e) {
                u32 pk = (u32)(u16)v0[e] | ((u32)(u16)v1[e] << 16);
                VtW[(vdg * 8 + e) * 36 + vc] = pk;
            }
        }
        __syncthreads();

#pragma unroll
        for (int qi = 0; qi < 2; ++qi) {
            const int qlo = qrow0 + qi * 16;
            if (kv0 > qlo + 15) continue;
            f32x4 S[4];
            __builtin_amdgcn_s_setprio(1);
#pragma unroll
            for (int kc = 0; kc < 4; ++kc) {
                const int row = kc * 16 + l15;
                const int sw = (row & 7) << 4;
                const char* Kb = (const char*)Ks;
                f32x4 s = zz;
                s16x8 bK0 = *(const s16x8*)(Kb + ((row * 128 + l4 * 16) ^ sw));
                s16x8 bK1 = *(const s16x8*)(Kb + ((row * 128 + 64 + l4 * 16) ^ sw));
                s = __builtin_amdgcn_mfma_f32_16x16x32_bf16(
                    __builtin_bit_cast(bf16x8, aQ[qi][0]), __builtin_bit_cast(bf16x8, bK0), s, 0, 0, 0);
                s = __builtin_amdgcn_mfma_f32_16x16x32_bf16(
                    __builtin_bit_cast(bf16x8, aQ[qi][1]), __builtin_bit_cast(bf16x8, bK1), s, 0, 0, 0);
#pragma unroll
                for (int r = 0; r < 4; ++r) S[kc][r] = s[r] * 0.125f;
            }
            __builtin_amdgcn_s_setprio(0);
            if (kv0 + 63 > qlo) {
#pragma unroll
                for (int kc = 0; kc < 4; ++kc) {
                    const int k = kv0 + kc * 16 + l15;
#pragma unroll
                    for (int r = 0; r < 4; ++r)
                        if (k > qlo + l4 * 4 + r) S[kc][r] = -3.0e38f;
                }
            }
            float mloc[4];
#pragma unroll
            for (int r = 0; r < 4; ++r)
                mloc[r] = fmaxf(fmaxf(S[0][r], S[1][r]), fmaxf(S[2][r], S[3][r]));
#pragma unroll
            for (int off = 1; off < 16; off <<= 1)
#pragma unroll
                for (int r = 0; r < 4; ++r) mloc[r] = fmaxf(mloc[r], __shfl_xor(mloc[r], off));
            bool stable = (mloc[0] <= mrow[qi][0] + 8.f) && (mloc[1] <= mrow[qi][1] + 8.f)
                       && (mloc[2] <= mrow[qi][2] + 8.f) && (mloc[3] <= mrow[qi][3] + 8.f);
            if (!__all(stable)) {
#pragma unroll
                for (int r = 0; r < 4; ++r) {
                    const float mnew = fmaxf(mrow[qi][r], mloc[r]);
                    const float al = __expf(mrow[qi][r] - mnew);
                    mrow[qi][r] = mnew;
                    lrow[qi][r] *= al;
#pragma unroll
                    for (int dj = 0; dj < 4; ++dj) O[qi][dj][r] *= al;
                }
            }
#pragma unroll
            for (int kc = 0; kc < 4; ++kc)
#pragma unroll
                for (int r = 0; r < 4; ++r) {
                    const float p = __expf(S[kc][r] - mrow[qi][r]);
                    Ps[wq][l4 * 4 + r][kc * 16 + l15] = f2bf(p);
                    lrow[qi][r] += p;
                }
            __builtin_amdgcn_s_setprio(1);
#pragma unroll
            for (int kk = 0; kk < 2; ++kk) {
                s16x8 aP = *(const s16x8*)&Ps[wq][l15][kk * 32 + l4 * 8];
#pragma unroll
                for (int dj = 0; dj < 4; ++dj) {
                    const int d = dj * 16 + l15;
                    const int c = (kk * 16 + l4 * 4 + 4 * ((d >> 3) & 7)) & 31;
                    s16x8 bV = *(const s16x8*)&VtW[d * 36 + c];
                    O[qi][dj] = __builtin_amdgcn_mfma_f32_16x16x32_bf16(
                        __builtin_bit_cast(bf16x8, aP), __builtin_bit_cast(bf16x8, bV),
                        O[qi][dj], 0, 0, 0);
                }
            }
            __builtin_amdgcn_s_setprio(0);
        }
    }
#pragma unroll
    for (int qi = 0; qi < 2; ++qi)
#pragma unroll
        for (int r = 0; r < 4; ++r) {
            float s = lrow[qi][r];
#pragma unroll
            for (int off = 1; off < 16; off <<= 1) s += __shfl_xor(s, off);
            lrow[qi][r] = s;
        }
#pragma unroll
    for (int qi = 0; qi < 2; ++qi)
#pragma unroll
        for (int dj = 0; dj < 4; ++dj)
#pragma unroll
            for (int r = 0; r < 4; ++r) {
                const size_t o = ((size_t)(b * 1024 + qrow0 + qi * 16 + l4 * 4 + r)) * 1024
                               + h * 64 + dj * 16 + l15;
                Og[o] = f2bf(O[qi][dj][r] / lrow[qi][r]);
            }
}

// ---------------- orchestration
extern "C" void kernel_launch(void* const* d_in, const int* in_sizes, int n_in,
                              void* d_out, int out_size, void* d_ws, size_t ws_size,
                              hipStream_t stream)
{
    (void)in_sizes; (void)n_in; (void)out_size; (void)ws_size;
    const int*   idx  = (const int*)  d_in[0];
    const float* tok  = (const float*)d_in[1];
    const float* pos  = (const float*)d_in[2];
    const float* Wq   = (const float*)d_in[3];
    const float* Wk   = (const float*)d_in[4];
    const float* Wv   = (const float*)d_in[5];
    const float* Wo   = (const float*)d_in[6];
    const float* bo   = (const float*)d_in[7];
    const float* ln1g = (const float*)d_in[8];
    const float* ln1b = (const float*)d_in[9];
    const float* ln2g = (const float*)d_in[10];
    const float* ln2b = (const float*)d_in[11];
    const float* W1   = (const float*)d_in[12];
    const float* b1   = (const float*)d_in[13];
    const float* W2   = (const float*)d_in[14];
    const float* b2   = (const float*)d_in[15];
    const float* lnfg = (const float*)d_in[16];
    const float* lnfb = (const float*)d_in[17];
    const float* Wh   = (const float*)d_in[18];
    const float* bh   = (const float*)d_in[19];

    char* p = (char*)d_ws;
    float* x  = (float*)p; p += (size_t)8192 * 1024 * 4;
    u16* h    = (u16*)p;   p += (size_t)8192 * 1024 * 2;
    u16* qkv  = (u16*)p;   p += (size_t)8192 * 3072 * 2;
    u16* ab   = (u16*)p;   p += (size_t)8192 * 1024 * 2;
    u16* fb   = (u16*)p;   p += (size_t)8192 * 4096 * 2;
    u16* wqT  = (u16*)p;   p += (size_t)1024 * 1024 * 2;   // wq/wk/wv contiguous -> [3072][1024]
    u16* wkT  = (u16*)p;   p += (size_t)1024 * 1024 * 2;
    u16* wvT  = (u16*)p;   p += (size_t)1024 * 1024 * 2;
    u16* woT  = (u16*)p;   p += (size_t)1024 * 1024 * 2;
    u16* w1T  = (u16*)p;   p += (size_t)1024 * 4096 * 2;
    u16* w2T  = (u16*)p;   p += (size_t)4096 * 1024 * 2;
    u16* whT  = (u16*)p;   p += (size_t)1024 * 256 * 2;
    (void)wkT; (void)wvT;

    const dim3 tb(32, 8);
    embed_k<<<8192, 256, 0, stream>>>(idx, tok, pos, x);
    for (int l = 0; l < 6; ++l) {
        transpose_all_k<<<12288, tb, 0, stream>>>(
            Wq + (size_t)l * 1048576, Wk + (size_t)l * 1048576,
            Wv + (size_t)l * 1048576, Wo + (size_t)l * 1048576,
            W1 + (size_t)l * 4194304, W2 + (size_t)l * 4194304,
            wqT, woT, w1T, w2T);

        ln_k<<<8192, 256, 0, stream>>>(x, ln1g + l * 1024, ln1b + l * 1024, h);
        gemm8p<0><<<384, 512, 0, stream>>>(h, wqT, nullptr, qkv, 3072, 1024, 12);
        attn_mfma_k<<<dim3(8, 128), 256, 0, stream>>>(qkv, ab);
        gemm_bt<1><<<512,  256, 0, stream>>>(ab, woT, bo + l * 1024, x, nullptr, nullptr, 1024, 1024, 8);
        ln_k<<<8192, 256, 0, stream>>>(x, ln2g + l * 1024, ln2b + l * 1024, h);
        gemm8p<2><<<512, 512, 0, stream>>>(h, w1T, b1 + l * 4096, fb, 4096, 1024, 16);
        gemm_bt<1><<<512,  256, 0, stream>>>(fb, w2T, b2 + l * 1024, x, nullptr, nullptr, 1024, 4096, 8);
    }
    transpose_k<<<dim3(8, 32), tb, 0, stream>>>(Wh, whT, 1024, 256);
    ln_k<<<8192, 256, 0, stream>>>(x, lnfg, lnfb, h);
    gemm_bt<3><<<128, 256, 0, stream>>>(h, whT, bh, nullptr, nullptr, (float*)d_out, 256, 1024, 2);
}

// Round 9
// 2609.064 us; speedup vs baseline: 1.1488x; 1.1488x over previous
//
#include <hip/hip_runtime.h>

typedef unsigned short u16;
typedef unsigned int   u32;
typedef __attribute__((ext_vector_type(4))) float  f32x4;
typedef __attribute__((ext_vector_type(8))) __bf16 bf16x8;
typedef __attribute__((ext_vector_type(8))) short  s16x8;
typedef __attribute__((ext_vector_type(4))) unsigned short u16x4;

#define DEVFN __device__ __forceinline__

DEVFN float bf2f(u16 u) {
    u32 v = ((u32)u) << 16;
    return __builtin_bit_cast(float, v);
}
DEVFN u16 f2bf(float f) {   // round-to-nearest-even
    u32 u = __builtin_bit_cast(u32, f);
    u32 r = u + 0x7FFFu + ((u >> 16) & 1u);
    return (u16)(r >> 16);
}

// async global->LDS, 16B per lane. LDS dest must be linear in lane order.
DEVFN void gload16(const void* g, void* l) {
    __builtin_amdgcn_global_load_lds(
        (const __attribute__((address_space(1))) void*)g,
        (__attribute__((address_space(3))) void*)l, 16, 0, 0);
}

// ---------------- embedding
__global__ __launch_bounds__(256) void embed_k(const int* __restrict__ idx,
                                               const float* __restrict__ tok,
                                               const float* __restrict__ pos,
                                               float* __restrict__ x)
{
    int i   = blockIdx.x * 256 + threadIdx.x;
    int row = i >> 8;
    int c   = (i & 255) << 2;
    int t   = row & 1023;
    int tk  = idx[row];
    float4 a = *(const float4*)&tok[(size_t)tk * 1024 + c];
    float4 p = *(const float4*)&pos[(size_t)t * 1024 + c];
    float4 r; r.x = a.x + p.x; r.y = a.y + p.y; r.z = a.z + p.z; r.w = a.w + p.w;
    *(float4*)&x[(size_t)row * 1024 + c] = r;
}

// ---------------- fp32 [K,N] -> bf16 [N,K] transpose (single matrix; head)
__global__ __launch_bounds__(256) void transpose_k(const float* __restrict__ W,
                                                   u16* __restrict__ Wt, int K, int N)
{
    __shared__ float tile[32][33];
    int n0 = blockIdx.x * 32, k0 = blockIdx.y * 32;
    int xx = threadIdx.x, ty = threadIdx.y;      // block (32,8)
#pragma unroll
    for (int yy = 0; yy < 4; ++yy) {
        int y = ty + yy * 8;
        tile[y][xx] = W[(size_t)(k0 + y) * N + n0 + xx];
    }
    __syncthreads();
#pragma unroll
    for (int yy = 0; yy < 4; ++yy) {
        int y = ty + yy * 8;
        Wt[(size_t)(n0 + y) * K + k0 + xx] = f2bf(tile[xx][y]);
    }
}

// ---------------- fused per-layer weight transpose: Wq/Wk/Wv/Wo/W1/W2 in ONE launch
__global__ __launch_bounds__(256) void transpose_all_k(
    const float* __restrict__ Wq, const float* __restrict__ Wk,
    const float* __restrict__ Wv, const float* __restrict__ Wo,
    const float* __restrict__ W1, const float* __restrict__ W2,
    u16* __restrict__ qkvT, u16* __restrict__ woT,
    u16* __restrict__ w1T, u16* __restrict__ w2T)
{
    __shared__ float tile[32][33];
    const int id = blockIdx.x;
    const float* W; u16* Wt; int K, N, bx, by;
    if (id < 3072) {
        const int m = id >> 10, t2 = id & 1023;
        W = (m == 0) ? Wq : (m == 1) ? Wk : Wv;
        Wt = qkvT + (size_t)m * 1024 * 1024;
        K = 1024; N = 1024; bx = t2 & 31; by = t2 >> 5;
    } else if (id < 4096) {
        const int t2 = id - 3072;
        W = Wo; Wt = woT; K = 1024; N = 1024; bx = t2 & 31; by = t2 >> 5;
    } else if (id < 8192) {
        const int t2 = id - 4096;
        W = W1; Wt = w1T; K = 1024; N = 4096; bx = t2 & 127; by = t2 >> 7;
    } else {
        const int t2 = id - 8192;
        W = W2; Wt = w2T; K = 4096; N = 1024; bx = t2 & 31; by = t2 >> 5;
    }
    const int n0 = bx * 32, k0 = by * 32;
    const int xx = threadIdx.x, ty = threadIdx.y;    // block (32,8)
#pragma unroll
    for (int yy = 0; yy < 4; ++yy) {
        const int y = ty + yy * 8;
        tile[y][xx] = W[(size_t)(k0 + y) * N + n0 + xx];
    }
    __syncthreads();
#pragma unroll
    for (int yy = 0; yy < 4; ++yy) {
        const int y = ty + yy * 8;
        Wt[(size_t)(n0 + y) * K + k0 + xx] = f2bf(tile[xx][y]);
    }
}

// ---------------- LayerNorm: fp32 in -> bf16 out, C=1024, one block per row
__global__ __launch_bounds__(256) void ln_k(const float* __restrict__ x,
                                            const float* __restrict__ g,
                                            const float* __restrict__ b,
                                            u16* __restrict__ out)
{
    const int row = blockIdx.x, tid = threadIdx.x;
    const float4 v = *(const float4*)&x[(size_t)row * 1024 + tid * 4];
    __shared__ float red[8];
    float s = v.x + v.y + v.z + v.w;
#pragma unroll
    for (int off = 32; off > 0; off >>= 1) s += __shfl_down(s, off);
    const int lane = tid & 63, wv = tid >> 6;
    if (lane == 0) red[wv] = s;
    __syncthreads();
    const float mu = (red[0] + red[1] + red[2] + red[3]) * (1.0f / 1024.0f);
    const float dx = v.x - mu, dy = v.y - mu, dz = v.z - mu, dw = v.w - mu;
    float s2 = dx * dx + dy * dy + dz * dz + dw * dw;
#pragma unroll
    for (int off = 32; off > 0; off >>= 1) s2 += __shfl_down(s2, off);
    if (lane == 0) red[4 + wv] = s2;
    __syncthreads();
    const float var = (red[4] + red[5] + red[6] + red[7]) * (1.0f / 1024.0f);
    const float rs  = rsqrtf(var + 1e-5f);
    const float4 gv = *(const float4*)&g[tid * 4];
    const float4 bv = *(const float4*)&b[tid * 4];
    u16x4 o;
    o.x = f2bf(dx * rs * gv.x + bv.x);
    o.y = f2bf(dy * rs * gv.y + bv.y);
    o.z = f2bf(dz * rs * gv.z + bv.z);
    o.w = f2bf(dw * rs * gv.w + bv.w);
    *(u16x4*)&out[(size_t)row * 1024 + tid * 4] = o;
}

// ---------------- bf16 MFMA GEMM (proven 128x128 dbuf):  C = A @ Bt^T (+epilogue)
// MODE 0: Ob = bf16(acc); 1: RES += acc+bias; 2: Ob = bf16(relu(acc+bias)); 3: Of = acc+bias
template <int MODE>
__global__ __launch_bounds__(256) void gemm_bt(const u16* __restrict__ A,
                                               const u16* __restrict__ Bt,
                                               const float* __restrict__ bias,
                                               float* __restrict__ RES,
                                               u16* __restrict__ Ob,
                                               float* __restrict__ Of,
                                               int N, int K, int ntx)
{
    __shared__ __align__(16) u16 As[2][128 * 32];
    __shared__ __align__(16) u16 Bs[2][128 * 32];
    const int tid  = threadIdx.x;
    const int lane = tid & 63, wave = tid >> 6;
    const int wr = wave >> 1, wc = wave & 1;
    const int l15 = lane & 15, l4 = lane >> 4;

    const int nwg = (int)gridDim.x;
    const int bid = (int)blockIdx.x;
    const int swz = (bid & 7) * (nwg >> 3) + (bid >> 3);
    const int n0 = (swz % ntx) * 128, m0 = (swz / ntx) * 128;

    f32x4 acc[4][4];
    const f32x4 zz = {0.f, 0.f, 0.f, 0.f};
#pragma unroll
    for (int i = 0; i < 4; ++i)
#pragma unroll
        for (int j = 0; j < 4; ++j) acc[i][j] = zz;

    const int r0 = tid >> 2, q0q = (tid & 3) * 8;
    const int r1 = (tid + 256) >> 2, q1q = ((tid + 256) & 3) * 8;
    const u16* Arow0 = &A [(size_t)(m0 + r0) * K + q0q];
    const u16* Brow0 = &Bt[(size_t)(n0 + r0) * K + q0q];
    const u16* Arow1 = &A [(size_t)(m0 + r1) * K + q1q];
    const u16* Brow1 = &Bt[(size_t)(n0 + r1) * K + q1q];

    gload16(Arow0, &As[0][tid * 8]);
    gload16(Brow0, &Bs[0][tid * 8]);
    gload16(Arow1, &As[0][(tid + 256) * 8]);
    gload16(Brow1, &Bs[0][(tid + 256) * 8]);
    __syncthreads();

    const int S = K >> 5;
    int cur = 0;
    for (int s = 0; s < S; ++s) {
        if (s + 1 < S) {
            const int kn = (s + 1) << 5;
            gload16(Arow0 + kn, &As[cur ^ 1][tid * 8]);
            gload16(Brow0 + kn, &Bs[cur ^ 1][tid * 8]);
            gload16(Arow1 + kn, &As[cur ^ 1][(tid + 256) * 8]);
            gload16(Brow1 + kn, &Bs[cur ^ 1][(tid + 256) * 8]);
        }
        s16x8 af[4], bw[4];
#pragma unroll
        for (int i = 0; i < 4; ++i)
            af[i] = *(const s16x8*)&As[cur][(wr * 64 + i * 16 + l15) * 32 + l4 * 8];
#pragma unroll
        for (int j = 0; j < 4; ++j)
            bw[j] = *(const s16x8*)&Bs[cur][(wc * 64 + j * 16 + l15) * 32 + l4 * 8];
#pragma unroll
        for (int i = 0; i < 4; ++i)
#pragma unroll
            for (int j = 0; j < 4; ++j)
                acc[i][j] = __builtin_amdgcn_mfma_f32_16x16x32_bf16(
                    __builtin_bit_cast(bf16x8, af[i]),
                    __builtin_bit_cast(bf16x8, bw[j]), acc[i][j], 0, 0, 0);
        __syncthreads();
        cur ^= 1;
    }

#pragma unroll
    for (int i = 0; i < 4; ++i) {
        const int rb = m0 + wr * 64 + i * 16 + l4 * 4;
#pragma unroll
        for (int j = 0; j < 4; ++j) {
            const int col = n0 + wc * 64 + j * 16 + l15;
            const float bval = (MODE == 0) ? 0.0f : bias[col];
#pragma unroll
            for (int r = 0; r < 4; ++r) {
                const size_t o = (size_t)(rb + r) * N + col;
                const float v = acc[i][j][r];
                if (MODE == 0)      Ob[o] = f2bf(v);
                else if (MODE == 1) RES[o] += v + bval;
                else if (MODE == 2) Ob[o] = f2bf(fmaxf(v + bval, 0.0f));
                else                Of[o] = v + bval;
            }
        }
    }
}

// ---------------- MFMA flash attention v5, causal.
// v4 + XCD-locality block mapping: batch b pinned to XCD b (K/V of one batch =
// 4MB = one XCD L2), heavy-qt-first preserved. grid(8,128) linear id x-major:
// id = xcd | (7-qt)<<3 | h<<6  (bijective).
__global__ __launch_bounds__(256) void attn_mfma_k(const u16* __restrict__ QKV,
                                                   u16* __restrict__ Og)
{
    const int id  = (int)(blockIdx.y * gridDim.x + blockIdx.x);
    const int b   = id & 7;                 // batch == XCD
    const int qt  = 7 - ((id >> 3) & 7);    // heavy blocks first
    const int h   = id >> 6;                // 0..15
    const int tid = threadIdx.x;
    const int wq  = tid >> 6, lane = tid & 63;
    const int l15 = lane & 15, l4 = lane >> 4;

    __shared__ __align__(16) u16 Ks[64 * 64];    // K rows, LINEAR + chunk XOR swizzle
    __shared__ __align__(16) u16 Vt[64][72];     // V^T rows d; u32 kv-pairs, rotated cols
    __shared__ __align__(16) u16 Ps[4][16][68];  // per-wave P
    u32* VtW = (u32*)&Vt[0][0];                  // row stride 36 u32

    const int qrow0 = qt * 128 + wq * 32;

    const u16* Qbase = QKV + (size_t)b * 1024 * 3072 + h * 64;
    const u16* Kbase = Qbase + 1024;
    const u16* Vbase = Qbase + 2048;

    s16x8 aQ[2][2];
#pragma unroll
    for (int qi = 0; qi < 2; ++qi) {
        const u16* qsrc = Qbase + (size_t)(qrow0 + qi * 16 + l15) * 3072;
        aQ[qi][0] = *(const s16x8*)(qsrc + l4 * 8);
        aQ[qi][1] = *(const s16x8*)(qsrc + 32 + l4 * 8);
    }

    f32x4 O[2][4];
    const f32x4 zz = {0.f, 0.f, 0.f, 0.f};
    float mrow[2][4], lrow[2][4];
#pragma unroll
    for (int qi = 0; qi < 2; ++qi) {
#pragma unroll
        for (int dj = 0; dj < 4; ++dj) O[qi][dj] = zz;
#pragma unroll
        for (int r = 0; r < 4; ++r) { mrow[qi][r] = -3.0e38f; lrow[qi][r] = 0.f; }
    }

    const int cw0 = tid, cw1 = 256 + tid;
    const int kr0 = cw0 >> 3, kc0 = ((cw0 & 7) ^ (kr0 & 7)) * 8;
    const int kr1 = cw1 >> 3, kc1 = ((cw1 & 7) ^ (kr1 & 7)) * 8;
    const int vp  = tid >> 3;
    const int vdg = tid & 7;
    const int vc  = (vp + 4 * vdg) & 31;

    const int ntiles = 2 * qt + 2;
    for (int t = 0; t < ntiles; ++t) {
        const int kv0 = t * 64;
        __syncthreads();
        gload16(Kbase + (size_t)(kv0 + kr0) * 3072 + kc0, &Ks[cw0 * 8]);
        gload16(Kbase + (size_t)(kv0 + kr1) * 3072 + kc1, &Ks[cw1 * 8]);
        {
            const u16* vb0 = Vbase + (size_t)(kv0 + 2 * vp) * 3072 + vdg * 8;
            s16x8 v0 = *(const s16x8*)vb0;
            s16x8 v1 = *(const s16x8*)(vb0 + 3072);
#pragma unroll
            for (int e = 0; e < 8; ++e) {
                u32 pk = (u32)(u16)v0[e] | ((u32)(u16)v1[e] << 16);
                VtW[(vdg * 8 + e) * 36 + vc] = pk;
            }
        }
        __syncthreads();

#pragma unroll
        for (int qi = 0; qi < 2; ++qi) {
            const int qlo = qrow0 + qi * 16;
            if (kv0 > qlo + 15) continue;
            f32x4 S[4];
            __builtin_amdgcn_s_setprio(1);
#pragma unroll
            for (int kc = 0; kc < 4; ++kc) {
                const int row = kc * 16 + l15;
                const int sw = (row & 7) << 4;
                const char* Kb = (const char*)Ks;
                f32x4 s = zz;
                s16x8 bK0 = *(const s16x8*)(Kb + ((row * 128 + l4 * 16) ^ sw));
                s16x8 bK1 = *(const s16x8*)(Kb + ((row * 128 + 64 + l4 * 16) ^ sw));
                s = __builtin_amdgcn_mfma_f32_16x16x32_bf16(
                    __builtin_bit_cast(bf16x8, aQ[qi][0]), __builtin_bit_cast(bf16x8, bK0), s, 0, 0, 0);
                s = __builtin_amdgcn_mfma_f32_16x16x32_bf16(
                    __builtin_bit_cast(bf16x8, aQ[qi][1]), __builtin_bit_cast(bf16x8, bK1), s, 0, 0, 0);
#pragma unroll
                for (int r = 0; r < 4; ++r) S[kc][r] = s[r] * 0.125f;
            }
            __builtin_amdgcn_s_setprio(0);
            if (kv0 + 63 > qlo) {
#pragma unroll
                for (int kc = 0; kc < 4; ++kc) {
                    const int k = kv0 + kc * 16 + l15;
#pragma unroll
                    for (int r = 0; r < 4; ++r)
                        if (k > qlo + l4 * 4 + r) S[kc][r] = -3.0e38f;
                }
            }
            float mloc[4];
#pragma unroll
            for (int r = 0; r < 4; ++r)
                mloc[r] = fmaxf(fmaxf(S[0][r], S[1][r]), fmaxf(S[2][r], S[3][r]));
#pragma unroll
            for (int off = 1; off < 16; off <<= 1)
#pragma unroll
                for (int r = 0; r < 4; ++r) mloc[r] = fmaxf(mloc[r], __shfl_xor(mloc[r], off));
            bool stable = (mloc[0] <= mrow[qi][0] + 8.f) && (mloc[1] <= mrow[qi][1] + 8.f)
                       && (mloc[2] <= mrow[qi][2] + 8.f) && (mloc[3] <= mrow[qi][3] + 8.f);
            if (!__all(stable)) {
#pragma unroll
                for (int r = 0; r < 4; ++r) {
                    const float mnew = fmaxf(mrow[qi][r], mloc[r]);
                    const float al = __expf(mrow[qi][r] - mnew);
                    mrow[qi][r] = mnew;
                    lrow[qi][r] *= al;
#pragma unroll
                    for (int dj = 0; dj < 4; ++dj) O[qi][dj][r] *= al;
                }
            }
#pragma unroll
            for (int kc = 0; kc < 4; ++kc)
#pragma unroll
                for (int r = 0; r < 4; ++r) {
                    const float p = __expf(S[kc][r] - mrow[qi][r]);
                    Ps[wq][l4 * 4 + r][kc * 16 + l15] = f2bf(p);
                    lrow[qi][r] += p;
                }
            __builtin_amdgcn_s_setprio(1);
#pragma unroll
            for (int kk = 0; kk < 2; ++kk) {
                s16x8 aP = *(const s16x8*)&Ps[wq][l15][kk * 32 + l4 * 8];
#pragma unroll
                for (int dj = 0; dj < 4; ++dj) {
                    const int d = dj * 16 + l15;
                    const int c = (kk * 16 + l4 * 4 + 4 * ((d >> 3) & 7)) & 31;
                    s16x8 bV = *(const s16x8*)&VtW[d * 36 + c];
                    O[qi][dj] = __builtin_amdgcn_mfma_f32_16x16x32_bf16(
                        __builtin_bit_cast(bf16x8, aP), __builtin_bit_cast(bf16x8, bV),
                        O[qi][dj], 0, 0, 0);
                }
            }
            __builtin_amdgcn_s_setprio(0);
        }
    }
#pragma unroll
    for (int qi = 0; qi < 2; ++qi)
#pragma unroll
        for (int r = 0; r < 4; ++r) {
            float s = lrow[qi][r];
#pragma unroll
            for (int off = 1; off < 16; off <<= 1) s += __shfl_xor(s, off);
            lrow[qi][r] = s;
        }
#pragma unroll
    for (int qi = 0; qi < 2; ++qi)
#pragma unroll
        for (int dj = 0; dj < 4; ++dj)
#pragma unroll
            for (int r = 0; r < 4; ++r) {
                const size_t o = ((size_t)(b * 1024 + qrow0 + qi * 16 + l4 * 4 + r)) * 1024
                               + h * 64 + dj * 16 + l15;
                Og[o] = f2bf(O[qi][dj][r] / lrow[qi][r]);
            }
}

// ---------------- orchestration
extern "C" void kernel_launch(void* const* d_in, const int* in_sizes, int n_in,
                              void* d_out, int out_size, void* d_ws, size_t ws_size,
                              hipStream_t stream)
{
    (void)in_sizes; (void)n_in; (void)out_size; (void)ws_size;
    const int*   idx  = (const int*)  d_in[0];
    const float* tok  = (const float*)d_in[1];
    const float* pos  = (const float*)d_in[2];
    const float* Wq   = (const float*)d_in[3];
    const float* Wk   = (const float*)d_in[4];
    const float* Wv   = (const float*)d_in[5];
    const float* Wo   = (const float*)d_in[6];
    const float* bo   = (const float*)d_in[7];
    const float* ln1g = (const float*)d_in[8];
    const float* ln1b = (const float*)d_in[9];
    const float* ln2g = (const float*)d_in[10];
    const float* ln2b = (const float*)d_in[11];
    const float* W1   = (const float*)d_in[12];
    const float* b1   = (const float*)d_in[13];
    const float* W2   = (const float*)d_in[14];
    const float* b2   = (const float*)d_in[15];
    const float* lnfg = (const float*)d_in[16];
    const float* lnfb = (const float*)d_in[17];
    const float* Wh   = (const float*)d_in[18];
    const float* bh   = (const float*)d_in[19];

    char* p = (char*)d_ws;
    float* x  = (float*)p; p += (size_t)8192 * 1024 * 4;
    u16* h    = (u16*)p;   p += (size_t)8192 * 1024 * 2;
    u16* qkv  = (u16*)p;   p += (size_t)8192 * 3072 * 2;
    u16* ab   = (u16*)p;   p += (size_t)8192 * 1024 * 2;
    u16* fb   = (u16*)p;   p += (size_t)8192 * 4096 * 2;
    u16* wqT  = (u16*)p;   p += (size_t)1024 * 1024 * 2;   // wq/wk/wv contiguous -> [3072][1024]
    u16* wkT  = (u16*)p;   p += (size_t)1024 * 1024 * 2;
    u16* wvT  = (u16*)p;   p += (size_t)1024 * 1024 * 2;
    u16* woT  = (u16*)p;   p += (size_t)1024 * 1024 * 2;
    u16* w1T  = (u16*)p;   p += (size_t)1024 * 4096 * 2;
    u16* w2T  = (u16*)p;   p += (size_t)4096 * 1024 * 2;
    u16* whT  = (u16*)p;   p += (size_t)1024 * 256 * 2;
    (void)wkT; (void)wvT;

    const dim3 tb(32, 8);
    embed_k<<<8192, 256, 0, stream>>>(idx, tok, pos, x);
    for (int l = 0; l < 6; ++l) {
        transpose_all_k<<<12288, tb, 0, stream>>>(
            Wq + (size_t)l * 1048576, Wk + (size_t)l * 1048576,
            Wv + (size_t)l * 1048576, Wo + (size_t)l * 1048576,
            W1 + (size_t)l * 4194304, W2 + (size_t)l * 4194304,
            wqT, woT, w1T, w2T);

        ln_k<<<8192, 256, 0, stream>>>(x, ln1g + l * 1024, ln1b + l * 1024, h);
        gemm_bt<0><<<1536, 256, 0, stream>>>(h, wqT, nullptr, nullptr, qkv, nullptr, 3072, 1024, 24);
        attn_mfma_k<<<dim3(8, 128), 256, 0, stream>>>(qkv, ab);
        gemm_bt<1><<<512,  256, 0, stream>>>(ab, woT, bo + l * 1024, x, nullptr, nullptr, 1024, 1024, 8);
        ln_k<<<8192, 256, 0, stream>>>(x, ln2g + l * 1024, ln2b + l * 1024, h);
        gemm_bt<2><<<2048, 256, 0, stream>>>(h, w1T, b1 + l * 4096, nullptr, fb, nullptr, 4096, 1024, 32);
        gemm_bt<1><<<512,  256, 0, stream>>>(fb, w2T, b2 + l * 1024, x, nullptr, nullptr, 1024, 4096, 8);
    }
    transpose_k<<<dim3(8, 32), tb, 0, stream>>>(Wh, whT, 1024, 256);
    ln_k<<<8192, 256, 0, stream>>>(x, lnfg, lnfb, h);
    gemm_bt<3><<<128, 256, 0, stream>>>(h, whT, bh, nullptr, nullptr, (float*)d_out, 256, 1024, 2);
}

// Round 10
// 2608.925 us; speedup vs baseline: 1.1488x; 1.0001x over previous
//
#include <hip/hip_runtime.h>

typedef unsigned short u16;
typedef unsigned int   u32;
typedef __attribute__((ext_vector_type(4))) float  f32x4;
typedef __attribute__((ext_vector_type(8))) __bf16 bf16x8;
typedef __attribute__((ext_vector_type(8))) short  s16x8;
typedef __attribute__((ext_vector_type(4))) unsigned short u16x4;

#define DEVFN __device__ __forceinline__

DEVFN float bf2f(u16 u) {
    u32 v = ((u32)u) << 16;
    return __builtin_bit_cast(float, v);
}
DEVFN u16 f2bf(float f) {   // round-to-nearest-even
    u32 u = __builtin_bit_cast(u32, f);
    u32 r = u + 0x7FFFu + ((u >> 16) & 1u);
    return (u16)(r >> 16);
}

// async global->LDS, 16B per lane. LDS dest must be linear in lane order.
DEVFN void gload16(const void* g, void* l) {
    __builtin_amdgcn_global_load_lds(
        (const __attribute__((address_space(1))) void*)g,
        (__attribute__((address_space(3))) void*)l, 16, 0, 0);
}

// ---------------- embedding
__global__ __launch_bounds__(256) void embed_k(const int* __restrict__ idx,
                                               const float* __restrict__ tok,
                                               const float* __restrict__ pos,
                                               float* __restrict__ x)
{
    int i   = blockIdx.x * 256 + threadIdx.x;
    int row = i >> 8;
    int c   = (i & 255) << 2;
    int t   = row & 1023;
    int tk  = idx[row];
    float4 a = *(const float4*)&tok[(size_t)tk * 1024 + c];
    float4 p = *(const float4*)&pos[(size_t)t * 1024 + c];
    float4 r; r.x = a.x + p.x; r.y = a.y + p.y; r.z = a.z + p.z; r.w = a.w + p.w;
    *(float4*)&x[(size_t)row * 1024 + c] = r;
}

// ---------------- fp32 [K,N] -> bf16 [N,K] transpose (single matrix; head)
__global__ __launch_bounds__(256) void transpose_k(const float* __restrict__ W,
                                                   u16* __restrict__ Wt, int K, int N)
{
    __shared__ float tile[32][33];
    int n0 = blockIdx.x * 32, k0 = blockIdx.y * 32;
    int xx = threadIdx.x, ty = threadIdx.y;      // block (32,8)
#pragma unroll
    for (int yy = 0; yy < 4; ++yy) {
        int y = ty + yy * 8;
        tile[y][xx] = W[(size_t)(k0 + y) * N + n0 + xx];
    }
    __syncthreads();
#pragma unroll
    for (int yy = 0; yy < 4; ++yy) {
        int y = ty + yy * 8;
        Wt[(size_t)(n0 + y) * K + k0 + xx] = f2bf(tile[xx][y]);
    }
}

// ---------------- fused per-layer weight transpose: Wq/Wk/Wv/Wo/W1/W2 in ONE launch
__global__ __launch_bounds__(256) void transpose_all_k(
    const float* __restrict__ Wq, const float* __restrict__ Wk,
    const float* __restrict__ Wv, const float* __restrict__ Wo,
    const float* __restrict__ W1, const float* __restrict__ W2,
    u16* __restrict__ qkvT, u16* __restrict__ woT,
    u16* __restrict__ w1T, u16* __restrict__ w2T)
{
    __shared__ float tile[32][33];
    const int id = blockIdx.x;
    const float* W; u16* Wt; int K, N, bx, by;
    if (id < 3072) {
        const int m = id >> 10, t2 = id & 1023;
        W = (m == 0) ? Wq : (m == 1) ? Wk : Wv;
        Wt = qkvT + (size_t)m * 1024 * 1024;
        K = 1024; N = 1024; bx = t2 & 31; by = t2 >> 5;
    } else if (id < 4096) {
        const int t2 = id - 3072;
        W = Wo; Wt = woT; K = 1024; N = 1024; bx = t2 & 31; by = t2 >> 5;
    } else if (id < 8192) {
        const int t2 = id - 4096;
        W = W1; Wt = w1T; K = 1024; N = 4096; bx = t2 & 127; by = t2 >> 7;
    } else {
        const int t2 = id - 8192;
        W = W2; Wt = w2T; K = 4096; N = 1024; bx = t2 & 31; by = t2 >> 5;
    }
    const int n0 = bx * 32, k0 = by * 32;
    const int xx = threadIdx.x, ty = threadIdx.y;    // block (32,8)
#pragma unroll
    for (int yy = 0; yy < 4; ++yy) {
        const int y = ty + yy * 8;
        tile[y][xx] = W[(size_t)(k0 + y) * N + n0 + xx];
    }
    __syncthreads();
#pragma unroll
    for (int yy = 0; yy < 4; ++yy) {
        const int y = ty + yy * 8;
        Wt[(size_t)(n0 + y) * K + k0 + xx] = f2bf(tile[xx][y]);
    }
}

// ---------------- LayerNorm: fp32 in -> bf16 out, C=1024, one block per row
__global__ __launch_bounds__(256) void ln_k(const float* __restrict__ x,
                                            const float* __restrict__ g,
                                            const float* __restrict__ b,
                                            u16* __restrict__ out)
{
    const int row = blockIdx.x, tid = threadIdx.x;
    const float4 v = *(const float4*)&x[(size_t)row * 1024 + tid * 4];
    __shared__ float red[8];
    float s = v.x + v.y + v.z + v.w;
#pragma unroll
    for (int off = 32; off > 0; off >>= 1) s += __shfl_down(s, off);
    const int lane = tid & 63, wv = tid >> 6;
    if (lane == 0) red[wv] = s;
    __syncthreads();
    const float mu = (red[0] + red[1] + red[2] + red[3]) * (1.0f / 1024.0f);
    const float dx = v.x - mu, dy = v.y - mu, dz = v.z - mu, dw = v.w - mu;
    float s2 = dx * dx + dy * dy + dz * dz + dw * dw;
#pragma unroll
    for (int off = 32; off > 0; off >>= 1) s2 += __shfl_down(s2, off);
    if (lane == 0) red[4 + wv] = s2;
    __syncthreads();
    const float var = (red[4] + red[5] + red[6] + red[7]) * (1.0f / 1024.0f);
    const float rs  = rsqrtf(var + 1e-5f);
    const float4 gv = *(const float4*)&g[tid * 4];
    const float4 bv = *(const float4*)&b[tid * 4];
    u16x4 o;
    o.x = f2bf(dx * rs * gv.x + bv.x);
    o.y = f2bf(dy * rs * gv.y + bv.y);
    o.z = f2bf(dz * rs * gv.z + bv.z);
    o.w = f2bf(dw * rs * gv.w + bv.w);
    *(u16x4*)&out[(size_t)row * 1024 + tid * 4] = o;
}

// ---------------- bf16 MFMA GEMM (proven 128x128 dbuf):  C = A @ Bt^T (+epilogue)
// MODE 0: Ob = bf16(acc); 1: RES += acc+bias; 2: Ob = bf16(relu(acc+bias)); 3: Of = acc+bias
template <int MODE>
__global__ __launch_bounds__(256) void gemm_bt(const u16* __restrict__ A,
                                               const u16* __restrict__ Bt,
                                               const float* __restrict__ bias,
                                               float* __restrict__ RES,
                                               u16* __restrict__ Ob,
                                               float* __restrict__ Of,
                                               int N, int K, int ntx)
{
    __shared__ __align__(16) u16 As[2][128 * 32];
    __shared__ __align__(16) u16 Bs[2][128 * 32];
    const int tid  = threadIdx.x;
    const int lane = tid & 63, wave = tid >> 6;
    const int wr = wave >> 1, wc = wave & 1;
    const int l15 = lane & 15, l4 = lane >> 4;

    const int nwg = (int)gridDim.x;
    const int bid = (int)blockIdx.x;
    const int swz = (bid & 7) * (nwg >> 3) + (bid >> 3);
    const int n0 = (swz % ntx) * 128, m0 = (swz / ntx) * 128;

    f32x4 acc[4][4];
    const f32x4 zz = {0.f, 0.f, 0.f, 0.f};
#pragma unroll
    for (int i = 0; i < 4; ++i)
#pragma unroll
        for (int j = 0; j < 4; ++j) acc[i][j] = zz;

    const int r0 = tid >> 2, q0q = (tid & 3) * 8;
    const int r1 = (tid + 256) >> 2, q1q = ((tid + 256) & 3) * 8;
    const u16* Arow0 = &A [(size_t)(m0 + r0) * K + q0q];
    const u16* Brow0 = &Bt[(size_t)(n0 + r0) * K + q0q];
    const u16* Arow1 = &A [(size_t)(m0 + r1) * K + q1q];
    const u16* Brow1 = &Bt[(size_t)(n0 + r1) * K + q1q];

    gload16(Arow0, &As[0][tid * 8]);
    gload16(Brow0, &Bs[0][tid * 8]);
    gload16(Arow1, &As[0][(tid + 256) * 8]);
    gload16(Brow1, &Bs[0][(tid + 256) * 8]);
    __syncthreads();

    const int S = K >> 5;
    int cur = 0;
    for (int s = 0; s < S; ++s) {
        if (s + 1 < S) {
            const int kn = (s + 1) << 5;
            gload16(Arow0 + kn, &As[cur ^ 1][tid * 8]);
            gload16(Brow0 + kn, &Bs[cur ^ 1][tid * 8]);
            gload16(Arow1 + kn, &As[cur ^ 1][(tid + 256) * 8]);
            gload16(Brow1 + kn, &Bs[cur ^ 1][(tid + 256) * 8]);
        }
        s16x8 af[4], bw[4];
#pragma unroll
        for (int i = 0; i < 4; ++i)
            af[i] = *(const s16x8*)&As[cur][(wr * 64 + i * 16 + l15) * 32 + l4 * 8];
#pragma unroll
        for (int j = 0; j < 4; ++j)
            bw[j] = *(const s16x8*)&Bs[cur][(wc * 64 + j * 16 + l15) * 32 + l4 * 8];
#pragma unroll
        for (int i = 0; i < 4; ++i)
#pragma unroll
            for (int j = 0; j < 4; ++j)
                acc[i][j] = __builtin_amdgcn_mfma_f32_16x16x32_bf16(
                    __builtin_bit_cast(bf16x8, af[i]),
                    __builtin_bit_cast(bf16x8, bw[j]), acc[i][j], 0, 0, 0);
        __syncthreads();
        cur ^= 1;
    }

#pragma unroll
    for (int i = 0; i < 4; ++i) {
        const int rb = m0 + wr * 64 + i * 16 + l4 * 4;
#pragma unroll
        for (int j = 0; j < 4; ++j) {
            const int col = n0 + wc * 64 + j * 16 + l15;
            const float bval = (MODE == 0) ? 0.0f : bias[col];
#pragma unroll
            for (int r = 0; r < 4; ++r) {
                const size_t o = (size_t)(rb + r) * N + col;
                const float v = acc[i][j][r];
                if (MODE == 0)      Ob[o] = f2bf(v);
                else if (MODE == 1) RES[o] += v + bval;
                else if (MODE == 2) Ob[o] = f2bf(fmaxf(v + bval, 0.0f));
                else                Of[o] = v + bval;
            }
        }
    }
}

// ---------------- MFMA flash attention v6, causal.
// v5 + complementary q-tile PAIRING: block handles q-tiles {p, 7-p} sharing K/V
// staging (light tile's kv range is a prefix of heavy's). Every block does
// exactly 16-2p staged tiles -> near-uniform durations, staging traffic -28%.
// grid (4,128) = 512 blocks; b = id&7 pins batch to XCD (K/V = 4MB = one L2).
__global__ __launch_bounds__(256) void attn_mfma_k(const u16* __restrict__ QKV,
                                                   u16* __restrict__ Og)
{
    const int id  = (int)(blockIdx.y * gridDim.x + blockIdx.x);
    const int b   = id & 7;                 // batch == XCD
    const int pp  = (id >> 3) & 3;          // pair index
    const int h   = id >> 5;                // 0..15
    const int tid = threadIdx.x;
    const int wq  = tid >> 6, lane = tid & 63;
    const int l15 = lane & 15, l4 = lane >> 4;

    __shared__ __align__(16) u16 Ks[64 * 64];    // K rows, LINEAR + chunk XOR swizzle
    __shared__ __align__(16) u16 Vt[64][72];     // V^T rows d; u32 kv-pairs, rotated cols
    __shared__ __align__(16) u16 Ps[4][16][68];  // per-wave P
    u32* VtW = (u32*)&Vt[0][0];                  // row stride 36 u32

    const int qbase0 = pp * 128 + wq * 32;        // light q-tile rows
    const int qbase1 = (7 - pp) * 128 + wq * 32;  // heavy q-tile rows

    const u16* Qbase = QKV + (size_t)b * 1024 * 3072 + h * 64;
    const u16* Kbase = Qbase + 1024;
    const u16* Vbase = Qbase + 2048;

    // 4 Q fragments: qi -> rows qsel(qi>>1) + (qi&1)*16
    s16x8 aQ[4][2];
#pragma unroll
    for (int qi = 0; qi < 4; ++qi) {
        const int qlo = ((qi >> 1) ? qbase1 : qbase0) + (qi & 1) * 16;
        const u16* qsrc = Qbase + (size_t)(qlo + l15) * 3072;
        aQ[qi][0] = *(const s16x8*)(qsrc + l4 * 8);
        aQ[qi][1] = *(const s16x8*)(qsrc + 32 + l4 * 8);
    }

    f32x4 O[4][4];
    const f32x4 zz = {0.f, 0.f, 0.f, 0.f};
    float mrow[4][4], lrow[4][4];
#pragma unroll
    for (int qi = 0; qi < 4; ++qi) {
#pragma unroll
        for (int dj = 0; dj < 4; ++dj) O[qi][dj] = zz;
#pragma unroll
        for (int r = 0; r < 4; ++r) { mrow[qi][r] = -3.0e38f; lrow[qi][r] = 0.f; }
    }

    const int cw0 = tid, cw1 = 256 + tid;
    const int kr0 = cw0 >> 3, kc0 = ((cw0 & 7) ^ (kr0 & 7)) * 8;
    const int kr1 = cw1 >> 3, kc1 = ((cw1 & 7) ^ (kr1 & 7)) * 8;
    const int vp  = tid >> 3;
    const int vdg = tid & 7;
    const int vc  = (vp + 4 * vdg) & 31;

    const int ntiles = 2 * (7 - pp) + 2;     // heavy tile's kv range covers both
    for (int t = 0; t < ntiles; ++t) {
        const int kv0 = t * 64;
        __syncthreads();
        gload16(Kbase + (size_t)(kv0 + kr0) * 3072 + kc0, &Ks[cw0 * 8]);
        gload16(Kbase + (size_t)(kv0 + kr1) * 3072 + kc1, &Ks[cw1 * 8]);
        {
            const u16* vb0 = Vbase + (size_t)(kv0 + 2 * vp) * 3072 + vdg * 8;
            s16x8 v0 = *(const s16x8*)vb0;
            s16x8 v1 = *(const s16x8*)(vb0 + 3072);
#pragma unroll
            for (int e = 0; e < 8; ++e) {
                u32 pk = (u32)(u16)v0[e] | ((u32)(u16)v1[e] << 16);
                VtW[(vdg * 8 + e) * 36 + vc] = pk;
            }
        }
        __syncthreads();

#pragma unroll
        for (int qi = 0; qi < 4; ++qi) {
            const int qlo = ((qi >> 1) ? qbase1 : qbase0) + (qi & 1) * 16;
            if (kv0 > qlo + 15) continue;            // fully masked frag (light tile exits early)
            f32x4 S[4];
            __builtin_amdgcn_s_setprio(1);
#pragma unroll
            for (int kc = 0; kc < 4; ++kc) {
                const int row = kc * 16 + l15;
                const int sw = (row & 7) << 4;
                const char* Kb = (const char*)Ks;
                f32x4 s = zz;
                s16x8 bK0 = *(const s16x8*)(Kb + ((row * 128 + l4 * 16) ^ sw));
                s16x8 bK1 = *(const s16x8*)(Kb + ((row * 128 + 64 + l4 * 16) ^ sw));
                s = __builtin_amdgcn_mfma_f32_16x16x32_bf16(
                    __builtin_bit_cast(bf16x8, aQ[qi][0]), __builtin_bit_cast(bf16x8, bK0), s, 0, 0, 0);
                s = __builtin_amdgcn_mfma_f32_16x16x32_bf16(
                    __builtin_bit_cast(bf16x8, aQ[qi][1]), __builtin_bit_cast(bf16x8, bK1), s, 0, 0, 0);
#pragma unroll
                for (int r = 0; r < 4; ++r) S[kc][r] = s[r] * 0.125f;
            }
            __builtin_amdgcn_s_setprio(0);
            if (kv0 + 63 > qlo) {
#pragma unroll
                for (int kc = 0; kc < 4; ++kc) {
                    const int k = kv0 + kc * 16 + l15;
#pragma unroll
                    for (int r = 0; r < 4; ++r)
                        if (k > qlo + l4 * 4 + r) S[kc][r] = -3.0e38f;
                }
            }
            float mloc[4];
#pragma unroll
            for (int r = 0; r < 4; ++r)
                mloc[r] = fmaxf(fmaxf(S[0][r], S[1][r]), fmaxf(S[2][r], S[3][r]));
#pragma unroll
            for (int off = 1; off < 16; off <<= 1)
#pragma unroll
                for (int r = 0; r < 4; ++r) mloc[r] = fmaxf(mloc[r], __shfl_xor(mloc[r], off));
            bool stable = (mloc[0] <= mrow[qi][0] + 8.f) && (mloc[1] <= mrow[qi][1] + 8.f)
                       && (mloc[2] <= mrow[qi][2] + 8.f) && (mloc[3] <= mrow[qi][3] + 8.f);
            if (!__all(stable)) {
#pragma unroll
                for (int r = 0; r < 4; ++r) {
                    const float mnew = fmaxf(mrow[qi][r], mloc[r]);
                    const float al = __expf(mrow[qi][r] - mnew);
                    mrow[qi][r] = mnew;
                    lrow[qi][r] *= al;
#pragma unroll
                    for (int dj = 0; dj < 4; ++dj) O[qi][dj][r] *= al;
                }
            }
#pragma unroll
            for (int kc = 0; kc < 4; ++kc)
#pragma unroll
                for (int r = 0; r < 4; ++r) {
                    const float p = __expf(S[kc][r] - mrow[qi][r]);
                    Ps[wq][l4 * 4 + r][kc * 16 + l15] = f2bf(p);
                    lrow[qi][r] += p;
                }
            __builtin_amdgcn_s_setprio(1);
#pragma unroll
            for (int kk = 0; kk < 2; ++kk) {
                s16x8 aP = *(const s16x8*)&Ps[wq][l15][kk * 32 + l4 * 8];
#pragma unroll
                for (int dj = 0; dj < 4; ++dj) {
                    const int d = dj * 16 + l15;
                    const int c = (kk * 16 + l4 * 4 + 4 * ((d >> 3) & 7)) & 31;
                    s16x8 bV = *(const s16x8*)&VtW[d * 36 + c];
                    O[qi][dj] = __builtin_amdgcn_mfma_f32_16x16x32_bf16(
                        __builtin_bit_cast(bf16x8, aP), __builtin_bit_cast(bf16x8, bV),
                        O[qi][dj], 0, 0, 0);
                }
            }
            __builtin_amdgcn_s_setprio(0);
        }
    }
    // epilogue: reduce partial l, then O/l for both q-tiles
#pragma unroll
    for (int qi = 0; qi < 4; ++qi)
#pragma unroll
        for (int r = 0; r < 4; ++r) {
            float s = lrow[qi][r];
#pragma unroll
            for (int off = 1; off < 16; off <<= 1) s += __shfl_xor(s, off);
            lrow[qi][r] = s;
        }
#pragma unroll
    for (int qi = 0; qi < 4; ++qi) {
        const int qlo = ((qi >> 1) ? qbase1 : qbase0) + (qi & 1) * 16;
#pragma unroll
        for (int dj = 0; dj < 4; ++dj)
#pragma unroll
            for (int r = 0; r < 4; ++r) {
                const size_t o = ((size_t)(b * 1024 + qlo + l4 * 4 + r)) * 1024
                               + h * 64 + dj * 16 + l15;
                Og[o] = f2bf(O[qi][dj][r] / lrow[qi][r]);
            }
    }
}

// ---------------- orchestration
extern "C" void kernel_launch(void* const* d_in, const int* in_sizes, int n_in,
                              void* d_out, int out_size, void* d_ws, size_t ws_size,
                              hipStream_t stream)
{
    (void)in_sizes; (void)n_in; (void)out_size; (void)ws_size;
    const int*   idx  = (const int*)  d_in[0];
    const float* tok  = (const float*)d_in[1];
    const float* pos  = (const float*)d_in[2];
    const float* Wq   = (const float*)d_in[3];
    const float* Wk   = (const float*)d_in[4];
    const float* Wv   = (const float*)d_in[5];
    const float* Wo   = (const float*)d_in[6];
    const float* bo   = (const float*)d_in[7];
    const float* ln1g = (const float*)d_in[8];
    const float* ln1b = (const float*)d_in[9];
    const float* ln2g = (const float*)d_in[10];
    const float* ln2b = (const float*)d_in[11];
    const float* W1   = (const float*)d_in[12];
    const float* b1   = (const float*)d_in[13];
    const float* W2   = (const float*)d_in[14];
    const float* b2   = (const float*)d_in[15];
    const float* lnfg = (const float*)d_in[16];
    const float* lnfb = (const float*)d_in[17];
    const float* Wh   = (const float*)d_in[18];
    const float* bh   = (const float*)d_in[19];

    char* p = (char*)d_ws;
    float* x  = (float*)p; p += (size_t)8192 * 1024 * 4;
    u16* h    = (u16*)p;   p += (size_t)8192 * 1024 * 2;
    u16* qkv  = (u16*)p;   p += (size_t)8192 * 3072 * 2;
    u16* ab   = (u16*)p;   p += (size_t)8192 * 1024 * 2;
    u16* fb   = (u16*)p;   p += (size_t)8192 * 4096 * 2;
    u16* wqT  = (u16*)p;   p += (size_t)1024 * 1024 * 2;   // wq/wk/wv contiguous -> [3072][1024]
    u16* wkT  = (u16*)p;   p += (size_t)1024 * 1024 * 2;
    u16* wvT  = (u16*)p;   p += (size_t)1024 * 1024 * 2;
    u16* woT  = (u16*)p;   p += (size_t)1024 * 1024 * 2;
    u16* w1T  = (u16*)p;   p += (size_t)1024 * 4096 * 2;
    u16* w2T  = (u16*)p;   p += (size_t)4096 * 1024 * 2;
    u16* whT  = (u16*)p;   p += (size_t)1024 * 256 * 2;
    (void)wkT; (void)wvT;

    const dim3 tb(32, 8);
    embed_k<<<8192, 256, 0, stream>>>(idx, tok, pos, x);
    for (int l = 0; l < 6; ++l) {
        transpose_all_k<<<12288, tb, 0, stream>>>(
            Wq + (size_t)l * 1048576, Wk + (size_t)l * 1048576,
            Wv + (size_t)l * 1048576, Wo + (size_t)l * 1048576,
            W1 + (size_t)l * 4194304, W2 + (size_t)l * 4194304,
            wqT, woT, w1T, w2T);

        ln_k<<<8192, 256, 0, stream>>>(x, ln1g + l * 1024, ln1b + l * 1024, h);
        gemm_bt<0><<<1536, 256, 0, stream>>>(h, wqT, nullptr, nullptr, qkv, nullptr, 3072, 1024, 24);
        attn_mfma_k<<<dim3(4, 128), 256, 0, stream>>>(qkv, ab);
        gemm_bt<1><<<512,  256, 0, stream>>>(ab, woT, bo + l * 1024, x, nullptr, nullptr, 1024, 1024, 8);
        ln_k<<<8192, 256, 0, stream>>>(x, ln2g + l * 1024, ln2b + l * 1024, h);
        gemm_bt<2><<<2048, 256, 0, stream>>>(h, w1T, b1 + l * 4096, nullptr, fb, nullptr, 4096, 1024, 32);
        gemm_bt<1><<<512,  256, 0, stream>>>(fb, w2T, b2 + l * 1024, x, nullptr, nullptr, 1024, 4096, 8);
    }
    transpose_k<<<dim3(8, 32), tb, 0, stream>>>(Wh, whT, 1024, 256);
    ln_k<<<8192, 256, 0, stream>>>(x, lnfg, lnfb, h);
    gemm_bt<3><<<128, 256, 0, stream>>>(h, whT, bh, nullptr, nullptr, (float*)d_out, 256, 1024, 2);
}

// Round 11
// 2601.773 us; speedup vs baseline: 1.1520x; 1.0027x over previous
//
#include <hip/hip_runtime.h>

typedef unsigned short u16;
typedef unsigned int   u32;
typedef __attribute__((ext_vector_type(4))) float  f32x4;
typedef __attribute__((ext_vector_type(8))) __bf16 bf16x8;
typedef __attribute__((ext_vector_type(8))) short  s16x8;
typedef __attribute__((ext_vector_type(4))) unsigned short u16x4;

#define DEVFN __device__ __forceinline__

DEVFN float bf2f(u16 u) {
    u32 v = ((u32)u) << 16;
    return __builtin_bit_cast(float, v);
}
DEVFN u16 f2bf(float f) {   // round-to-nearest-even
    u32 u = __builtin_bit_cast(u32, f);
    u32 r = u + 0x7FFFu + ((u >> 16) & 1u);
    return (u16)(r >> 16);
}

// async global->LDS, 16B per lane. LDS dest must be linear in lane order.
DEVFN void gload16(const void* g, void* l) {
    __builtin_amdgcn_global_load_lds(
        (const __attribute__((address_space(1))) void*)g,
        (__attribute__((address_space(3))) void*)l, 16, 0, 0);
}

// ---------------- embedding
__global__ __launch_bounds__(256) void embed_k(const int* __restrict__ idx,
                                               const float* __restrict__ tok,
                                               const float* __restrict__ pos,
                                               float* __restrict__ x)
{
    int i   = blockIdx.x * 256 + threadIdx.x;
    int row = i >> 8;
    int c   = (i & 255) << 2;
    int t   = row & 1023;
    int tk  = idx[row];
    float4 a = *(const float4*)&tok[(size_t)tk * 1024 + c];
    float4 p = *(const float4*)&pos[(size_t)t * 1024 + c];
    float4 r; r.x = a.x + p.x; r.y = a.y + p.y; r.z = a.z + p.z; r.w = a.w + p.w;
    *(float4*)&x[(size_t)row * 1024 + c] = r;
}

// ---------------- fp32 [K,N] -> bf16 [N,K] transpose (single matrix; head)
__global__ __launch_bounds__(256) void transpose_k(const float* __restrict__ W,
                                                   u16* __restrict__ Wt, int K, int N)
{
    __shared__ float tile[32][33];
    int n0 = blockIdx.x * 32, k0 = blockIdx.y * 32;
    int xx = threadIdx.x, ty = threadIdx.y;      // block (32,8)
#pragma unroll
    for (int yy = 0; yy < 4; ++yy) {
        int y = ty + yy * 8;
        tile[y][xx] = W[(size_t)(k0 + y) * N + n0 + xx];
    }
    __syncthreads();
#pragma unroll
    for (int yy = 0; yy < 4; ++yy) {
        int y = ty + yy * 8;
        Wt[(size_t)(n0 + y) * K + k0 + xx] = f2bf(tile[xx][y]);
    }
}

// ---------------- fused per-layer weight transpose: Wq/Wk/Wv/Wo/W1/W2 in ONE launch
__global__ __launch_bounds__(256) void transpose_all_k(
    const float* __restrict__ Wq, const float* __restrict__ Wk,
    const float* __restrict__ Wv, const float* __restrict__ Wo,
    const float* __restrict__ W1, const float* __restrict__ W2,
    u16* __restrict__ qkvT, u16* __restrict__ woT,
    u16* __restrict__ w1T, u16* __restrict__ w2T)
{
    __shared__ float tile[32][33];
    const int id = blockIdx.x;
    const float* W; u16* Wt; int K, N, bx, by;
    if (id < 3072) {
        const int m = id >> 10, t2 = id & 1023;
        W = (m == 0) ? Wq : (m == 1) ? Wk : Wv;
        Wt = qkvT + (size_t)m * 1024 * 1024;
        K = 1024; N = 1024; bx = t2 & 31; by = t2 >> 5;
    } else if (id < 4096) {
        const int t2 = id - 3072;
        W = Wo; Wt = woT; K = 1024; N = 1024; bx = t2 & 31; by = t2 >> 5;
    } else if (id < 8192) {
        const int t2 = id - 4096;
        W = W1; Wt = w1T; K = 1024; N = 4096; bx = t2 & 127; by = t2 >> 7;
    } else {
        const int t2 = id - 8192;
        W = W2; Wt = w2T; K = 4096; N = 1024; bx = t2 & 31; by = t2 >> 5;
    }
    const int n0 = bx * 32, k0 = by * 32;
    const int xx = threadIdx.x, ty = threadIdx.y;    // block (32,8)
#pragma unroll
    for (int yy = 0; yy < 4; ++yy) {
        const int y = ty + yy * 8;
        tile[y][xx] = W[(size_t)(k0 + y) * N + n0 + xx];
    }
    __syncthreads();
#pragma unroll
    for (int yy = 0; yy < 4; ++yy) {
        const int y = ty + yy * 8;
        Wt[(size_t)(n0 + y) * K + k0 + xx] = f2bf(tile[xx][y]);
    }
}

// ---------------- LayerNorm: fp32 in -> bf16 out, C=1024, one block per row
__global__ __launch_bounds__(256) void ln_k(const float* __restrict__ x,
                                            const float* __restrict__ g,
                                            const float* __restrict__ b,
                                            u16* __restrict__ out)
{
    const int row = blockIdx.x, tid = threadIdx.x;
    const float4 v = *(const float4*)&x[(size_t)row * 1024 + tid * 4];
    __shared__ float red[8];
    float s = v.x + v.y + v.z + v.w;
#pragma unroll
    for (int off = 32; off > 0; off >>= 1) s += __shfl_down(s, off);
    const int lane = tid & 63, wv = tid >> 6;
    if (lane == 0) red[wv] = s;
    __syncthreads();
    const float mu = (red[0] + red[1] + red[2] + red[3]) * (1.0f / 1024.0f);
    const float dx = v.x - mu, dy = v.y - mu, dz = v.z - mu, dw = v.w - mu;
    float s2 = dx * dx + dy * dy + dz * dz + dw * dw;
#pragma unroll
    for (int off = 32; off > 0; off >>= 1) s2 += __shfl_down(s2, off);
    if (lane == 0) red[4 + wv] = s2;
    __syncthreads();
    const float var = (red[4] + red[5] + red[6] + red[7]) * (1.0f / 1024.0f);
    const float rs  = rsqrtf(var + 1e-5f);
    const float4 gv = *(const float4*)&g[tid * 4];
    const float4 bv = *(const float4*)&b[tid * 4];
    u16x4 o;
    o.x = f2bf(dx * rs * gv.x + bv.x);
    o.y = f2bf(dy * rs * gv.y + bv.y);
    o.z = f2bf(dz * rs * gv.z + bv.z);
    o.w = f2bf(dw * rs * gv.w + bv.w);
    *(u16x4*)&out[(size_t)row * 1024 + tid * 4] = o;
}

// ---------------- bf16 MFMA GEMM (proven 128x128 dbuf):  C = A @ Bt^T (+epilogue)
// MODE 0: Ob = bf16(acc); 1: RES += acc+bias; 2: Ob = bf16(relu(acc+bias)); 3: Of = acc+bias
template <int MODE>
__global__ __launch_bounds__(256) void gemm_bt(const u16* __restrict__ A,
                                               const u16* __restrict__ Bt,
                                               const float* __restrict__ bias,
                                               float* __restrict__ RES,
                                               u16* __restrict__ Ob,
                                               float* __restrict__ Of,
                                               int N, int K, int ntx)
{
    __shared__ __align__(16) u16 As[2][128 * 32];
    __shared__ __align__(16) u16 Bs[2][128 * 32];
    const int tid  = threadIdx.x;
    const int lane = tid & 63, wave = tid >> 6;
    const int wr = wave >> 1, wc = wave & 1;
    const int l15 = lane & 15, l4 = lane >> 4;

    const int nwg = (int)gridDim.x;
    const int bid = (int)blockIdx.x;
    const int swz = (bid & 7) * (nwg >> 3) + (bid >> 3);
    const int n0 = (swz % ntx) * 128, m0 = (swz / ntx) * 128;

    f32x4 acc[4][4];
    const f32x4 zz = {0.f, 0.f, 0.f, 0.f};
#pragma unroll
    for (int i = 0; i < 4; ++i)
#pragma unroll
        for (int j = 0; j < 4; ++j) acc[i][j] = zz;

    const int r0 = tid >> 2, q0q = (tid & 3) * 8;
    const int r1 = (tid + 256) >> 2, q1q = ((tid + 256) & 3) * 8;
    const u16* Arow0 = &A [(size_t)(m0 + r0) * K + q0q];
    const u16* Brow0 = &Bt[(size_t)(n0 + r0) * K + q0q];
    const u16* Arow1 = &A [(size_t)(m0 + r1) * K + q1q];
    const u16* Brow1 = &Bt[(size_t)(n0 + r1) * K + q1q];

    gload16(Arow0, &As[0][tid * 8]);
    gload16(Brow0, &Bs[0][tid * 8]);
    gload16(Arow1, &As[0][(tid + 256) * 8]);
    gload16(Brow1, &Bs[0][(tid + 256) * 8]);
    __syncthreads();

    const int S = K >> 5;
    int cur = 0;
    for (int s = 0; s < S; ++s) {
        if (s + 1 < S) {
            const int kn = (s + 1) << 5;
            gload16(Arow0 + kn, &As[cur ^ 1][tid * 8]);
            gload16(Brow0 + kn, &Bs[cur ^ 1][tid * 8]);
            gload16(Arow1 + kn, &As[cur ^ 1][(tid + 256) * 8]);
            gload16(Brow1 + kn, &Bs[cur ^ 1][(tid + 256) * 8]);
        }
        s16x8 af[4], bw[4];
#pragma unroll
        for (int i = 0; i < 4; ++i)
            af[i] = *(const s16x8*)&As[cur][(wr * 64 + i * 16 + l15) * 32 + l4 * 8];
#pragma unroll
        for (int j = 0; j < 4; ++j)
            bw[j] = *(const s16x8*)&Bs[cur][(wc * 64 + j * 16 + l15) * 32 + l4 * 8];
#pragma unroll
        for (int i = 0; i < 4; ++i)
#pragma unroll
            for (int j = 0; j < 4; ++j)
                acc[i][j] = __builtin_amdgcn_mfma_f32_16x16x32_bf16(
                    __builtin_bit_cast(bf16x8, af[i]),
                    __builtin_bit_cast(bf16x8, bw[j]), acc[i][j], 0, 0, 0);
        __syncthreads();
        cur ^= 1;
    }

#pragma unroll
    for (int i = 0; i < 4; ++i) {
        const int rb = m0 + wr * 64 + i * 16 + l4 * 4;
#pragma unroll
        for (int j = 0; j < 4; ++j) {
            const int col = n0 + wc * 64 + j * 16 + l15;
            const float bval = (MODE == 0) ? 0.0f : bias[col];
#pragma unroll
            for (int r = 0; r < 4; ++r) {
                const size_t o = (size_t)(rb + r) * N + col;
                const float v = acc[i][j][r];
                if (MODE == 0)      Ob[o] = f2bf(v);
                else if (MODE == 1) RES[o] += v + bval;
                else if (MODE == 2) Ob[o] = f2bf(fmaxf(v + bval, 0.0f));
                else                Of[o] = v + bval;
            }
        }
    }
}

// ---------------- MFMA flash attention v7, causal.
// v6 + T14 async-stage split: issue K/V REG loads for tile t+1 BEFORE compute(t)
// (HBM latency hides under compute), LDS writes after the post-compute barrier.
// Single-buffer LDS (26 KB), 2 barriers/tile, XOR-swizzled K via swizzled WRITE addr.
// Pairing {p, 7-p} + XCD pinning (b = id&7) kept from v6.
__global__ __launch_bounds__(256) void attn_mfma_k(const u16* __restrict__ QKV,
                                                   u16* __restrict__ Og)
{
    const int id  = (int)(blockIdx.y * gridDim.x + blockIdx.x);
    const int b   = id & 7;                 // batch == XCD
    const int pp  = (id >> 3) & 3;          // pair index
    const int h   = id >> 5;                // 0..15
    const int tid = threadIdx.x;
    const int wq  = tid >> 6, lane = tid & 63;
    const int l15 = lane & 15, l4 = lane >> 4;

    __shared__ __align__(16) u16 Ks[64 * 64];    // K rows, chunk-XOR swizzled
    __shared__ __align__(16) u16 Vt[64][72];     // V^T rows d; u32 kv-pairs, rotated cols
    __shared__ __align__(16) u16 Ps[4][16][68];  // per-wave P
    u32* VtW = (u32*)&Vt[0][0];                  // row stride 36 u32

    const int qbase0 = pp * 128 + wq * 32;        // light q-tile rows
    const int qbase1 = (7 - pp) * 128 + wq * 32;  // heavy q-tile rows

    const u16* Qbase = QKV + (size_t)b * 1024 * 3072 + h * 64;
    const u16* Kbase = Qbase + 1024;
    const u16* Vbase = Qbase + 2048;

    // 4 Q fragments: qi -> rows qsel(qi>>1) + (qi&1)*16
    s16x8 aQ[4][2];
#pragma unroll
    for (int qi = 0; qi < 4; ++qi) {
        const int qlo = ((qi >> 1) ? qbase1 : qbase0) + (qi & 1) * 16;
        const u16* qsrc = Qbase + (size_t)(qlo + l15) * 3072;
        aQ[qi][0] = *(const s16x8*)(qsrc + l4 * 8);
        aQ[qi][1] = *(const s16x8*)(qsrc + 32 + l4 * 8);
    }

    f32x4 O[4][4];
    const f32x4 zz = {0.f, 0.f, 0.f, 0.f};
    float mrow[4][4], lrow[4][4];
#pragma unroll
    for (int qi = 0; qi < 4; ++qi) {
#pragma unroll
        for (int dj = 0; dj < 4; ++dj) O[qi][dj] = zz;
#pragma unroll
        for (int r = 0; r < 4; ++r) { mrow[qi][r] = -3.0e38f; lrow[qi][r] = 0.f; }
    }

    // K reg-staging: thread loads rows srow, srow+32, 8 u16 at col soff (linear
    // source); writes LDS at chunk soff^( (row&7)*8 ) — same involution the
    // read side uses ((row&7)<<4 byte XOR).
    const int srow = tid >> 3;
    const int soff = (tid & 7) * 8;
    const int kw0  = srow * 64 + (soff ^ ((srow & 7) * 8));          // u16 index
    const int kw1  = (srow + 32) * 64 + (soff ^ ((srow & 7) * 8));   // (srow+32)&7 == srow&7
    // V staging (reg->LDS transpose, rotated cols)
    const int vp  = tid >> 3;
    const int vdg = tid & 7;
    const int vc  = (vp + 4 * vdg) & 31;

    const int ntiles = 2 * (7 - pp) + 2;     // heavy tile's kv range covers both
    s16x8 kr0, kr1, vr0, vr1;

    // prologue: load + write tile 0
    {
        const u16* kb0 = Kbase + (size_t)srow * 3072 + soff;
        kr0 = *(const s16x8*)kb0;
        kr1 = *(const s16x8*)(kb0 + (size_t)32 * 3072);
        const u16* vb0 = Vbase + (size_t)(2 * vp) * 3072 + vdg * 8;
        vr0 = *(const s16x8*)vb0;
        vr1 = *(const s16x8*)(vb0 + 3072);
        *(s16x8*)&Ks[kw0] = kr0;
        *(s16x8*)&Ks[kw1] = kr1;
#pragma unroll
        for (int e = 0; e < 8; ++e) {
            u32 pk = (u32)(u16)vr0[e] | ((u32)(u16)vr1[e] << 16);
            VtW[(vdg * 8 + e) * 36 + vc] = pk;
        }
    }
    __syncthreads();

    for (int t = 0; t < ntiles; ++t) {
        const int kv0 = t * 64;
        const bool more = (t + 1 < ntiles);
        if (more) {   // issue next-tile loads; latency hides under compute(t)
            const u16* kb0 = Kbase + (size_t)(kv0 + 64 + srow) * 3072 + soff;
            kr0 = *(const s16x8*)kb0;
            kr1 = *(const s16x8*)(kb0 + (size_t)32 * 3072);
            const u16* vb0 = Vbase + (size_t)(kv0 + 64 + 2 * vp) * 3072 + vdg * 8;
            vr0 = *(const s16x8*)vb0;
            vr1 = *(const s16x8*)(vb0 + 3072);
        }

#pragma unroll
        for (int qi = 0; qi < 4; ++qi) {
            const int qlo = ((qi >> 1) ? qbase1 : qbase0) + (qi & 1) * 16;
            if (kv0 > qlo + 15) continue;            // fully masked frag
            f32x4 S[4];
            __builtin_amdgcn_s_setprio(1);
#pragma unroll
            for (int kc = 0; kc < 4; ++kc) {
                const int row = kc * 16 + l15;
                const int sw = (row & 7) << 4;
                const char* Kb = (const char*)Ks;
                f32x4 s = zz;
                s16x8 bK0 = *(const s16x8*)(Kb + ((row * 128 + l4 * 16) ^ sw));
                s16x8 bK1 = *(const s16x8*)(Kb + ((row * 128 + 64 + l4 * 16) ^ sw));
                s = __builtin_amdgcn_mfma_f32_16x16x32_bf16(
                    __builtin_bit_cast(bf16x8, aQ[qi][0]), __builtin_bit_cast(bf16x8, bK0), s, 0, 0, 0);
                s = __builtin_amdgcn_mfma_f32_16x16x32_bf16(
                    __builtin_bit_cast(bf16x8, aQ[qi][1]), __builtin_bit_cast(bf16x8, bK1), s, 0, 0, 0);
#pragma unroll
                for (int r = 0; r < 4; ++r) S[kc][r] = s[r] * 0.125f;
            }
            __builtin_amdgcn_s_setprio(0);
            if (kv0 + 63 > qlo) {
#pragma unroll
                for (int kc = 0; kc < 4; ++kc) {
                    const int k = kv0 + kc * 16 + l15;
#pragma unroll
                    for (int r = 0; r < 4; ++r)
                        if (k > qlo + l4 * 4 + r) S[kc][r] = -3.0e38f;
                }
            }
            float mloc[4];
#pragma unroll
            for (int r = 0; r < 4; ++r)
                mloc[r] = fmaxf(fmaxf(S[0][r], S[1][r]), fmaxf(S[2][r], S[3][r]));
#pragma unroll
            for (int off = 1; off < 16; off <<= 1)
#pragma unroll
                for (int r = 0; r < 4; ++r) mloc[r] = fmaxf(mloc[r], __shfl_xor(mloc[r], off));
            bool stable = (mloc[0] <= mrow[qi][0] + 8.f) && (mloc[1] <= mrow[qi][1] + 8.f)
                       && (mloc[2] <= mrow[qi][2] + 8.f) && (mloc[3] <= mrow[qi][3] + 8.f);
            if (!__all(stable)) {
#pragma unroll
                for (int r = 0; r < 4; ++r) {
                    const float mnew = fmaxf(mrow[qi][r], mloc[r]);
                    const float al = __expf(mrow[qi][r] - mnew);
                    mrow[qi][r] = mnew;
                    lrow[qi][r] *= al;
#pragma unroll
                    for (int dj = 0; dj < 4; ++dj) O[qi][dj][r] *= al;
                }
            }
#pragma unroll
            for (int kc = 0; kc < 4; ++kc)
#pragma unroll
                for (int r = 0; r < 4; ++r) {
                    const float p = __expf(S[kc][r] - mrow[qi][r]);
                    Ps[wq][l4 * 4 + r][kc * 16 + l15] = f2bf(p);
                    lrow[qi][r] += p;
                }
            __builtin_amdgcn_s_setprio(1);
#pragma unroll
            for (int kk = 0; kk < 2; ++kk) {
                s16x8 aP = *(const s16x8*)&Ps[wq][l15][kk * 32 + l4 * 8];
#pragma unroll
                for (int dj = 0; dj < 4; ++dj) {
                    const int d = dj * 16 + l15;
                    const int c = (kk * 16 + l4 * 4 + 4 * ((d >> 3) & 7)) & 31;
                    s16x8 bV = *(const s16x8*)&VtW[d * 36 + c];
                    O[qi][dj] = __builtin_amdgcn_mfma_f32_16x16x32_bf16(
                        __builtin_bit_cast(bf16x8, aP), __builtin_bit_cast(bf16x8, bV),
                        O[qi][dj], 0, 0, 0);
                }
            }
            __builtin_amdgcn_s_setprio(0);
        }

        __syncthreads();   // all waves done reading Ks/Vt of tile t
        if (more) {        // write-late: staged regs -> LDS (cheap drain)
            *(s16x8*)&Ks[kw0] = kr0;
            *(s16x8*)&Ks[kw1] = kr1;
#pragma unroll
            for (int e = 0; e < 8; ++e) {
                u32 pk = (u32)(u16)vr0[e] | ((u32)(u16)vr1[e] << 16);
                VtW[(vdg * 8 + e) * 36 + vc] = pk;
            }
        }
        __syncthreads();   // staging visible
    }
    // epilogue: reduce partial l, then O/l for both q-tiles
#pragma unroll
    for (int qi = 0; qi < 4; ++qi)
#pragma unroll
        for (int r = 0; r < 4; ++r) {
            float s = lrow[qi][r];
#pragma unroll
            for (int off = 1; off < 16; off <<= 1) s += __shfl_xor(s, off);
            lrow[qi][r] = s;
        }
#pragma unroll
    for (int qi = 0; qi < 4; ++qi) {
        const int qlo = ((qi >> 1) ? qbase1 : qbase0) + (qi & 1) * 16;
#pragma unroll
        for (int dj = 0; dj < 4; ++dj)
#pragma unroll
            for (int r = 0; r < 4; ++r) {
                const size_t o = ((size_t)(b * 1024 + qlo + l4 * 4 + r)) * 1024
                               + h * 64 + dj * 16 + l15;
                Og[o] = f2bf(O[qi][dj][r] / lrow[qi][r]);
            }
    }
}

// ---------------- orchestration
extern "C" void kernel_launch(void* const* d_in, const int* in_sizes, int n_in,
                              void* d_out, int out_size, void* d_ws, size_t ws_size,
                              hipStream_t stream)
{
    (void)in_sizes; (void)n_in; (void)out_size; (void)ws_size;
    const int*   idx  = (const int*)  d_in[0];
    const float* tok  = (const float*)d_in[1];
    const float* pos  = (const float*)d_in[2];
    const float* Wq   = (const float*)d_in[3];
    const float* Wk   = (const float*)d_in[4];
    const float* Wv   = (const float*)d_in[5];
    const float* Wo   = (const float*)d_in[6];
    const float* bo   = (const float*)d_in[7];
    const float* ln1g = (const float*)d_in[8];
    const float* ln1b = (const float*)d_in[9];
    const float* ln2g = (const float*)d_in[10];
    const float* ln2b = (const float*)d_in[11];
    const float* W1   = (const float*)d_in[12];
    const float* b1   = (const float*)d_in[13];
    const float* W2   = (const float*)d_in[14];
    const float* b2   = (const float*)d_in[15];
    const float* lnfg = (const float*)d_in[16];
    const float* lnfb = (const float*)d_in[17];
    const float* Wh   = (const float*)d_in[18];
    const float* bh   = (const float*)d_in[19];

    char* p = (char*)d_ws;
    float* x  = (float*)p; p += (size_t)8192 * 1024 * 4;
    u16* h    = (u16*)p;   p += (size_t)8192 * 1024 * 2;
    u16* qkv  = (u16*)p;   p += (size_t)8192 * 3072 * 2;
    u16* ab   = (u16*)p;   p += (size_t)8192 * 1024 * 2;
    u16* fb   = (u16*)p;   p += (size_t)8192 * 4096 * 2;
    u16* wqT  = (u16*)p;   p += (size_t)1024 * 1024 * 2;   // wq/wk/wv contiguous -> [3072][1024]
    u16* wkT  = (u16*)p;   p += (size_t)1024 * 1024 * 2;
    u16* wvT  = (u16*)p;   p += (size_t)1024 * 1024 * 2;
    u16* woT  = (u16*)p;   p += (size_t)1024 * 1024 * 2;
    u16* w1T  = (u16*)p;   p += (size_t)1024 * 4096 * 2;
    u16* w2T  = (u16*)p;   p += (size_t)4096 * 1024 * 2;
    u16* whT  = (u16*)p;   p += (size_t)1024 * 256 * 2;
    (void)wkT; (void)wvT;

    const dim3 tb(32, 8);
    embed_k<<<8192, 256, 0, stream>>>(idx, tok, pos, x);
    for (int l = 0; l < 6; ++l) {
        transpose_all_k<<<12288, tb, 0, stream>>>(
            Wq + (size_t)l * 1048576, Wk + (size_t)l * 1048576,
            Wv + (size_t)l * 1048576, Wo + (size_t)l * 1048576,
            W1 + (size_t)l * 4194304, W2 + (size_t)l * 4194304,
            wqT, woT, w1T, w2T);

        ln_k<<<8192, 256, 0, stream>>>(x, ln1g + l * 1024, ln1b + l * 1024, h);
        gemm_bt<0><<<1536, 256, 0, stream>>>(h, wqT, nullptr, nullptr, qkv, nullptr, 3072, 1024, 24);
        attn_mfma_k<<<dim3(4, 128), 256, 0, stream>>>(qkv, ab);
        gemm_bt<1><<<512,  256, 0, stream>>>(ab, woT, bo + l * 1024, x, nullptr, nullptr, 1024, 1024, 8);
        ln_k<<<8192, 256, 0, stream>>>(x, ln2g + l * 1024, ln2b + l * 1024, h);
        gemm_bt<2><<<2048, 256, 0, stream>>>(h, w1T, b1 + l * 4096, nullptr, fb, nullptr, 4096, 1024, 32);
        gemm_bt<1><<<512,  256, 0, stream>>>(fb, w2T, b2 + l * 1024, x, nullptr, nullptr, 1024, 4096, 8);
    }
    transpose_k<<<dim3(8, 32), tb, 0, stream>>>(Wh, whT, 1024, 256);
    ln_k<<<8192, 256, 0, stream>>>(x, lnfg, lnfb, h);
    gemm_bt<3><<<128, 256, 0, stream>>>(h, whT, bh, nullptr, nullptr, (float*)d_out, 256, 1024, 2);
}

// Round 12
// 2551.163 us; speedup vs baseline: 1.1748x; 1.0198x over previous
//
#include <hip/hip_runtime.h>

typedef unsigned short u16;
typedef unsigned int   u32;
typedef __attribute__((ext_vector_type(4))) float  f32x4;
typedef __attribute__((ext_vector_type(8))) __bf16 bf16x8;
typedef __attribute__((ext_vector_type(8))) short  s16x8;
typedef __attribute__((ext_vector_type(4))) unsigned short u16x4;

#define DEVFN __device__ __forceinline__

DEVFN float bf2f(u16 u) {
    u32 v = ((u32)u) << 16;
    return __builtin_bit_cast(float, v);
}
DEVFN u16 f2bf(float f) {   // round-to-nearest-even
    u32 u = __builtin_bit_cast(u32, f);
    u32 r = u + 0x7FFFu + ((u >> 16) & 1u);
    return (u16)(r >> 16);
}

// async global->LDS, 16B per lane. LDS dest must be linear in lane order.
DEVFN void gload16(const void* g, void* l) {
    __builtin_amdgcn_global_load_lds(
        (const __attribute__((address_space(1))) void*)g,
        (__attribute__((address_space(3))) void*)l, 16, 0, 0);
}

// ---------------- embedding
__global__ __launch_bounds__(256) void embed_k(const int* __restrict__ idx,
                                               const float* __restrict__ tok,
                                               const float* __restrict__ pos,
                                               float* __restrict__ x)
{
    int i   = blockIdx.x * 256 + threadIdx.x;
    int row = i >> 8;
    int c   = (i & 255) << 2;
    int t   = row & 1023;
    int tk  = idx[row];
    float4 a = *(const float4*)&tok[(size_t)tk * 1024 + c];
    float4 p = *(const float4*)&pos[(size_t)t * 1024 + c];
    float4 r; r.x = a.x + p.x; r.y = a.y + p.y; r.z = a.z + p.z; r.w = a.w + p.w;
    *(float4*)&x[(size_t)row * 1024 + c] = r;
}

// ---------------- fp32 [K,N] -> bf16 [N,K] transpose (single matrix; head)
__global__ __launch_bounds__(256) void transpose_k(const float* __restrict__ W,
                                                   u16* __restrict__ Wt, int K, int N)
{
    __shared__ float tile[32][33];
    int n0 = blockIdx.x * 32, k0 = blockIdx.y * 32;
    int xx = threadIdx.x, ty = threadIdx.y;      // block (32,8)
#pragma unroll
    for (int yy = 0; yy < 4; ++yy) {
        int y = ty + yy * 8;
        tile[y][xx] = W[(size_t)(k0 + y) * N + n0 + xx];
    }
    __syncthreads();
#pragma unroll
    for (int yy = 0; yy < 4; ++yy) {
        int y = ty + yy * 8;
        Wt[(size_t)(n0 + y) * K + k0 + xx] = f2bf(tile[xx][y]);
    }
}

// ---------------- fused per-layer weight transpose: Wq/Wk/Wv/Wo/W1/W2 in ONE launch
__global__ __launch_bounds__(256) void transpose_all_k(
    const float* __restrict__ Wq, const float* __restrict__ Wk,
    const float* __restrict__ Wv, const float* __restrict__ Wo,
    const float* __restrict__ W1, const float* __restrict__ W2,
    u16* __restrict__ qkvT, u16* __restrict__ woT,
    u16* __restrict__ w1T, u16* __restrict__ w2T)
{
    __shared__ float tile[32][33];
    const int id = blockIdx.x;
    const float* W; u16* Wt; int K, N, bx, by;
    if (id < 3072) {
        const int m = id >> 10, t2 = id & 1023;
        W = (m == 0) ? Wq : (m == 1) ? Wk : Wv;
        Wt = qkvT + (size_t)m * 1024 * 1024;
        K = 1024; N = 1024; bx = t2 & 31; by = t2 >> 5;
    } else if (id < 4096) {
        const int t2 = id - 3072;
        W = Wo; Wt = woT; K = 1024; N = 1024; bx = t2 & 31; by = t2 >> 5;
    } else if (id < 8192) {
        const int t2 = id - 4096;
        W = W1; Wt = w1T; K = 1024; N = 4096; bx = t2 & 127; by = t2 >> 7;
    } else {
        const int t2 = id - 8192;
        W = W2; Wt = w2T; K = 4096; N = 1024; bx = t2 & 31; by = t2 >> 5;
    }
    const int n0 = bx * 32, k0 = by * 32;
    const int xx = threadIdx.x, ty = threadIdx.y;    // block (32,8)
#pragma unroll
    for (int yy = 0; yy < 4; ++yy) {
        const int y = ty + yy * 8;
        tile[y][xx] = W[(size_t)(k0 + y) * N + n0 + xx];
    }
    __syncthreads();
#pragma unroll
    for (int yy = 0; yy < 4; ++yy) {
        const int y = ty + yy * 8;
        Wt[(size_t)(n0 + y) * K + k0 + xx] = f2bf(tile[xx][y]);
    }
}

// ---------------- LayerNorm: fp32 in -> bf16 out, C=1024, one block per row
__global__ __launch_bounds__(256) void ln_k(const float* __restrict__ x,
                                            const float* __restrict__ g,
                                            const float* __restrict__ b,
                                            u16* __restrict__ out)
{
    const int row = blockIdx.x, tid = threadIdx.x;
    const float4 v = *(const float4*)&x[(size_t)row * 1024 + tid * 4];
    __shared__ float red[8];
    float s = v.x + v.y + v.z + v.w;
#pragma unroll
    for (int off = 32; off > 0; off >>= 1) s += __shfl_down(s, off);
    const int lane = tid & 63, wv = tid >> 6;
    if (lane == 0) red[wv] = s;
    __syncthreads();
    const float mu = (red[0] + red[1] + red[2] + red[3]) * (1.0f / 1024.0f);
    const float dx = v.x - mu, dy = v.y - mu, dz = v.z - mu, dw = v.w - mu;
    float s2 = dx * dx + dy * dy + dz * dz + dw * dw;
#pragma unroll
    for (int off = 32; off > 0; off >>= 1) s2 += __shfl_down(s2, off);
    if (lane == 0) red[4 + wv] = s2;
    __syncthreads();
    const float var = (red[4] + red[5] + red[6] + red[7]) * (1.0f / 1024.0f);
    const float rs  = rsqrtf(var + 1e-5f);
    const float4 gv = *(const float4*)&g[tid * 4];
    const float4 bv = *(const float4*)&b[tid * 4];
    u16x4 o;
    o.x = f2bf(dx * rs * gv.x + bv.x);
    o.y = f2bf(dy * rs * gv.y + bv.y);
    o.z = f2bf(dz * rs * gv.z + bv.z);
    o.w = f2bf(dw * rs * gv.w + bv.w);
    *(u16x4*)&out[(size_t)row * 1024 + tid * 4] = o;
}

// ---------------- bf16 MFMA GEMM (proven 128x128 dbuf; for qkv/ffn1)
// MODE 0: Ob = bf16(acc); 2: Ob = bf16(relu(acc+bias))
template <int MODE>
__global__ __launch_bounds__(256) void gemm_bt(const u16* __restrict__ A,
                                               const u16* __restrict__ Bt,
                                               const float* __restrict__ bias,
                                               float* __restrict__ RES,
                                               u16* __restrict__ Ob,
                                               float* __restrict__ Of,
                                               int N, int K, int ntx)
{
    __shared__ __align__(16) u16 As[2][128 * 32];
    __shared__ __align__(16) u16 Bs[2][128 * 32];
    const int tid  = threadIdx.x;
    const int lane = tid & 63, wave = tid >> 6;
    const int wr = wave >> 1, wc = wave & 1;
    const int l15 = lane & 15, l4 = lane >> 4;

    const int nwg = (int)gridDim.x;
    const int bid = (int)blockIdx.x;
    const int swz = (bid & 7) * (nwg >> 3) + (bid >> 3);
    const int n0 = (swz % ntx) * 128, m0 = (swz / ntx) * 128;

    f32x4 acc[4][4];
    const f32x4 zz = {0.f, 0.f, 0.f, 0.f};
#pragma unroll
    for (int i = 0; i < 4; ++i)
#pragma unroll
        for (int j = 0; j < 4; ++j) acc[i][j] = zz;

    const int r0 = tid >> 2, q0q = (tid & 3) * 8;
    const int r1 = (tid + 256) >> 2, q1q = ((tid + 256) & 3) * 8;
    const u16* Arow0 = &A [(size_t)(m0 + r0) * K + q0q];
    const u16* Brow0 = &Bt[(size_t)(n0 + r0) * K + q0q];
    const u16* Arow1 = &A [(size_t)(m0 + r1) * K + q1q];
    const u16* Brow1 = &Bt[(size_t)(n0 + r1) * K + q1q];

    gload16(Arow0, &As[0][tid * 8]);
    gload16(Brow0, &Bs[0][tid * 8]);
    gload16(Arow1, &As[0][(tid + 256) * 8]);
    gload16(Brow1, &Bs[0][(tid + 256) * 8]);
    __syncthreads();

    const int S = K >> 5;
    int cur = 0;
    for (int s = 0; s < S; ++s) {
        if (s + 1 < S) {
            const int kn = (s + 1) << 5;
            gload16(Arow0 + kn, &As[cur ^ 1][tid * 8]);
            gload16(Brow0 + kn, &Bs[cur ^ 1][tid * 8]);
            gload16(Arow1 + kn, &As[cur ^ 1][(tid + 256) * 8]);
            gload16(Brow1 + kn, &Bs[cur ^ 1][(tid + 256) * 8]);
        }
        s16x8 af[4], bw[4];
#pragma unroll
        for (int i = 0; i < 4; ++i)
            af[i] = *(const s16x8*)&As[cur][(wr * 64 + i * 16 + l15) * 32 + l4 * 8];
#pragma unroll
        for (int j = 0; j < 4; ++j)
            bw[j] = *(const s16x8*)&Bs[cur][(wc * 64 + j * 16 + l15) * 32 + l4 * 8];
#pragma unroll
        for (int i = 0; i < 4; ++i)
#pragma unroll
            for (int j = 0; j < 4; ++j)
                acc[i][j] = __builtin_amdgcn_mfma_f32_16x16x32_bf16(
                    __builtin_bit_cast(bf16x8, af[i]),
                    __builtin_bit_cast(bf16x8, bw[j]), acc[i][j], 0, 0, 0);
        __syncthreads();
        cur ^= 1;
    }

#pragma unroll
    for (int i = 0; i < 4; ++i) {
        const int rb = m0 + wr * 64 + i * 16 + l4 * 4;
#pragma unroll
        for (int j = 0; j < 4; ++j) {
            const int col = n0 + wc * 64 + j * 16 + l15;
            const float bval = (MODE == 0) ? 0.0f : bias[col];
#pragma unroll
            for (int r = 0; r < 4; ++r) {
                const size_t o = (size_t)(rb + r) * N + col;
                const float v = acc[i][j][r];
                if (MODE == 0)      Ob[o] = f2bf(v);
                else if (MODE == 1) RES[o] += v + bval;
                else if (MODE == 2) Ob[o] = f2bf(fmaxf(v + bval, 0.0f));
                else                Of[o] = v + bval;
            }
        }
    }
}

// ---------------- 128x64-tile GEMM for grid-starved N=1024/256 outputs (wo/ffn2/head)
// Same 2-barrier dbuf structure; 24 KB LDS -> 4+ blocks/CU from a 1024-block grid.
// MODE 1: RES += acc+bias (fp32); MODE 3: Of = acc+bias (fp32 out).
template <int MODE>
__global__ __launch_bounds__(256) void gemm_n64(const u16* __restrict__ A,
                                                const u16* __restrict__ Bt,
                                                const float* __restrict__ bias,
                                                float* __restrict__ RES,
                                                float* __restrict__ Of,
                                                int N, int K, int ntx)
{
    __shared__ __align__(16) u16 As[2][128 * 32];
    __shared__ __align__(16) u16 Bs[2][64 * 32];
    const int tid  = threadIdx.x;
    const int lane = tid & 63, wave = tid >> 6;
    const int wr = wave >> 1, wc = wave & 1;       // 2x2 waves of 64x32
    const int l15 = lane & 15, l4 = lane >> 4;

    const int nwg = (int)gridDim.x;
    const int bid = (int)blockIdx.x;
    const int swz = (bid & 7) * (nwg >> 3) + (bid >> 3);
    const int n0 = (swz % ntx) * 64, m0 = (swz / ntx) * 128;

    f32x4 acc[4][2];
    const f32x4 zz = {0.f, 0.f, 0.f, 0.f};
#pragma unroll
    for (int i = 0; i < 4; ++i)
#pragma unroll
        for (int j = 0; j < 2; ++j) acc[i][j] = zz;

    // A: 512 chunks (2/thread), B: 256 chunks (1/thread); chunk c -> row c>>2, q c&3
    const int r0 = tid >> 2, q0q = (tid & 3) * 8;
    const int r1 = (tid + 256) >> 2, q1q = ((tid + 256) & 3) * 8;
    const u16* Arow0 = &A [(size_t)(m0 + r0) * K + q0q];
    const u16* Arow1 = &A [(size_t)(m0 + r1) * K + q1q];
    const u16* Brow0 = &Bt[(size_t)(n0 + r0) * K + q0q];

    gload16(Arow0, &As[0][tid * 8]);
    gload16(Arow1, &As[0][(tid + 256) * 8]);
    gload16(Brow0, &Bs[0][tid * 8]);
    __syncthreads();

    const int S = K >> 5;
    int cur = 0;
    for (int s = 0; s < S; ++s) {
        if (s + 1 < S) {
            const int kn = (s + 1) << 5;
            gload16(Arow0 + kn, &As[cur ^ 1][tid * 8]);
            gload16(Arow1 + kn, &As[cur ^ 1][(tid + 256) * 8]);
            gload16(Brow0 + kn, &Bs[cur ^ 1][tid * 8]);
        }
        s16x8 af[4], bw[2];
#pragma unroll
        for (int i = 0; i < 4; ++i)
            af[i] = *(const s16x8*)&As[cur][(wr * 64 + i * 16 + l15) * 32 + l4 * 8];
#pragma unroll
        for (int j = 0; j < 2; ++j)
            bw[j] = *(const s16x8*)&Bs[cur][(wc * 32 + j * 16 + l15) * 32 + l4 * 8];
#pragma unroll
        for (int i = 0; i < 4; ++i)
#pragma unroll
            for (int j = 0; j < 2; ++j)
                acc[i][j] = __builtin_amdgcn_mfma_f32_16x16x32_bf16(
                    __builtin_bit_cast(bf16x8, af[i]),
                    __builtin_bit_cast(bf16x8, bw[j]), acc[i][j], 0, 0, 0);
        __syncthreads();
        cur ^= 1;
    }

#pragma unroll
    for (int i = 0; i < 4; ++i) {
        const int rb = m0 + wr * 64 + i * 16 + l4 * 4;
#pragma unroll
        for (int j = 0; j < 2; ++j) {
            const int col = n0 + wc * 32 + j * 16 + l15;
            const float bval = bias[col];
#pragma unroll
            for (int r = 0; r < 4; ++r) {
                const size_t o = (size_t)(rb + r) * N + col;
                const float v = acc[i][j][r];
                if (MODE == 1) RES[o] += v + bval;
                else           Of[o] = v + bval;
            }
        }
    }
}

// ---------------- MFMA flash attention v7 (unchanged), causal.
__global__ __launch_bounds__(256) void attn_mfma_k(const u16* __restrict__ QKV,
                                                   u16* __restrict__ Og)
{
    const int id  = (int)(blockIdx.y * gridDim.x + blockIdx.x);
    const int b   = id & 7;                 // batch == XCD
    const int pp  = (id >> 3) & 3;          // pair index
    const int h   = id >> 5;                // 0..15
    const int tid = threadIdx.x;
    const int wq  = tid >> 6, lane = tid & 63;
    const int l15 = lane & 15, l4 = lane >> 4;

    __shared__ __align__(16) u16 Ks[64 * 64];    // K rows, chunk-XOR swizzled
    __shared__ __align__(16) u16 Vt[64][72];     // V^T rows d; u32 kv-pairs, rotated cols
    __shared__ __align__(16) u16 Ps[4][16][68];  // per-wave P
    u32* VtW = (u32*)&Vt[0][0];                  // row stride 36 u32

    const int qbase0 = pp * 128 + wq * 32;        // light q-tile rows
    const int qbase1 = (7 - pp) * 128 + wq * 32;  // heavy q-tile rows

    const u16* Qbase = QKV + (size_t)b * 1024 * 3072 + h * 64;
    const u16* Kbase = Qbase + 1024;
    const u16* Vbase = Qbase + 2048;

    s16x8 aQ[4][2];
#pragma unroll
    for (int qi = 0; qi < 4; ++qi) {
        const int qlo = ((qi >> 1) ? qbase1 : qbase0) + (qi & 1) * 16;
        const u16* qsrc = Qbase + (size_t)(qlo + l15) * 3072;
        aQ[qi][0] = *(const s16x8*)(qsrc + l4 * 8);
        aQ[qi][1] = *(const s16x8*)(qsrc + 32 + l4 * 8);
    }

    f32x4 O[4][4];
    const f32x4 zz = {0.f, 0.f, 0.f, 0.f};
    float mrow[4][4], lrow[4][4];
#pragma unroll
    for (int qi = 0; qi < 4; ++qi) {
#pragma unroll
        for (int dj = 0; dj < 4; ++dj) O[qi][dj] = zz;
#pragma unroll
        for (int r = 0; r < 4; ++r) { mrow[qi][r] = -3.0e38f; lrow[qi][r] = 0.f; }
    }

    const int srow = tid >> 3;
    const int soff = (tid & 7) * 8;
    const int kw0  = srow * 64 + (soff ^ ((srow & 7) * 8));
    const int kw1  = (srow + 32) * 64 + (soff ^ ((srow & 7) * 8));
    const int vp  = tid >> 3;
    const int vdg = tid & 7;
    const int vc  = (vp + 4 * vdg) & 31;

    const int ntiles = 2 * (7 - pp) + 2;
    s16x8 kr0, kr1, vr0, vr1;

    {
        const u16* kb0 = Kbase + (size_t)srow * 3072 + soff;
        kr0 = *(const s16x8*)kb0;
        kr1 = *(const s16x8*)(kb0 + (size_t)32 * 3072);
        const u16* vb0 = Vbase + (size_t)(2 * vp) * 3072 + vdg * 8;
        vr0 = *(const s16x8*)vb0;
        vr1 = *(const s16x8*)(vb0 + 3072);
        *(s16x8*)&Ks[kw0] = kr0;
        *(s16x8*)&Ks[kw1] = kr1;
#pragma unroll
        for (int e = 0; e < 8; ++e) {
            u32 pk = (u32)(u16)vr0[e] | ((u32)(u16)vr1[e] << 16);
            VtW[(vdg * 8 + e) * 36 + vc] = pk;
        }
    }
    __syncthreads();

    for (int t = 0; t < ntiles; ++t) {
        const int kv0 = t * 64;
        const bool more = (t + 1 < ntiles);
        if (more) {
            const u16* kb0 = Kbase + (size_t)(kv0 + 64 + srow) * 3072 + soff;
            kr0 = *(const s16x8*)kb0;
            kr1 = *(const s16x8*)(kb0 + (size_t)32 * 3072);
            const u16* vb0 = Vbase + (size_t)(kv0 + 64 + 2 * vp) * 3072 + vdg * 8;
            vr0 = *(const s16x8*)vb0;
            vr1 = *(const s16x8*)(vb0 + 3072);
        }

#pragma unroll
        for (int qi = 0; qi < 4; ++qi) {
            const int qlo = ((qi >> 1) ? qbase1 : qbase0) + (qi & 1) * 16;
            if (kv0 > qlo + 15) continue;
            f32x4 S[4];
            __builtin_amdgcn_s_setprio(1);
#pragma unroll
            for (int kc = 0; kc < 4; ++kc) {
                const int row = kc * 16 + l15;
                const int sw = (row & 7) << 4;
                const char* Kb = (const char*)Ks;
                f32x4 s = zz;
                s16x8 bK0 = *(const s16x8*)(Kb + ((row * 128 + l4 * 16) ^ sw));
                s16x8 bK1 = *(const s16x8*)(Kb + ((row * 128 + 64 + l4 * 16) ^ sw));
                s = __builtin_amdgcn_mfma_f32_16x16x32_bf16(
                    __builtin_bit_cast(bf16x8, aQ[qi][0]), __builtin_bit_cast(bf16x8, bK0), s, 0, 0, 0);
                s = __builtin_amdgcn_mfma_f32_16x16x32_bf16(
                    __builtin_bit_cast(bf16x8, aQ[qi][1]), __builtin_bit_cast(bf16x8, bK1), s, 0, 0, 0);
#pragma unroll
                for (int r = 0; r < 4; ++r) S[kc][r] = s[r] * 0.125f;
            }
            __builtin_amdgcn_s_setprio(0);
            if (kv0 + 63 > qlo) {
#pragma unroll
                for (int kc = 0; kc < 4; ++kc) {
                    const int k = kv0 + kc * 16 + l15;
#pragma unroll
                    for (int r = 0; r < 4; ++r)
                        if (k > qlo + l4 * 4 + r) S[kc][r] = -3.0e38f;
                }
            }
            float mloc[4];
#pragma unroll
            for (int r = 0; r < 4; ++r)
                mloc[r] = fmaxf(fmaxf(S[0][r], S[1][r]), fmaxf(S[2][r], S[3][r]));
#pragma unroll
            for (int off = 1; off < 16; off <<= 1)
#pragma unroll
                for (int r = 0; r < 4; ++r) mloc[r] = fmaxf(mloc[r], __shfl_xor(mloc[r], off));
            bool stable = (mloc[0] <= mrow[qi][0] + 8.f) && (mloc[1] <= mrow[qi][1] + 8.f)
                       && (mloc[2] <= mrow[qi][2] + 8.f) && (mloc[3] <= mrow[qi][3] + 8.f);
            if (!__all(stable)) {
#pragma unroll
                for (int r = 0; r < 4; ++r) {
                    const float mnew = fmaxf(mrow[qi][r], mloc[r]);
                    const float al = __expf(mrow[qi][r] - mnew);
                    mrow[qi][r] = mnew;
                    lrow[qi][r] *= al;
#pragma unroll
                    for (int dj = 0; dj < 4; ++dj) O[qi][dj][r] *= al;
                }
            }
#pragma unroll
            for (int kc = 0; kc < 4; ++kc)
#pragma unroll
                for (int r = 0; r < 4; ++r) {
                    const float p = __expf(S[kc][r] - mrow[qi][r]);
                    Ps[wq][l4 * 4 + r][kc * 16 + l15] = f2bf(p);
                    lrow[qi][r] += p;
                }
            __builtin_amdgcn_s_setprio(1);
#pragma unroll
            for (int kk = 0; kk < 2; ++kk) {
                s16x8 aP = *(const s16x8*)&Ps[wq][l15][kk * 32 + l4 * 8];
#pragma unroll
                for (int dj = 0; dj < 4; ++dj) {
                    const int d = dj * 16 + l15;
                    const int c = (kk * 16 + l4 * 4 + 4 * ((d >> 3) & 7)) & 31;
                    s16x8 bV = *(const s16x8*)&VtW[d * 36 + c];
                    O[qi][dj] = __builtin_amdgcn_mfma_f32_16x16x32_bf16(
                        __builtin_bit_cast(bf16x8, aP), __builtin_bit_cast(bf16x8, bV),
                        O[qi][dj], 0, 0, 0);
                }
            }
            __builtin_amdgcn_s_setprio(0);
        }

        __syncthreads();
        if (more) {
            *(s16x8*)&Ks[kw0] = kr0;
            *(s16x8*)&Ks[kw1] = kr1;
#pragma unroll
            for (int e = 0; e < 8; ++e) {
                u32 pk = (u32)(u16)vr0[e] | ((u32)(u16)vr1[e] << 16);
                VtW[(vdg * 8 + e) * 36 + vc] = pk;
            }
        }
        __syncthreads();
    }
#pragma unroll
    for (int qi = 0; qi < 4; ++qi)
#pragma unroll
        for (int r = 0; r < 4; ++r) {
            float s = lrow[qi][r];
#pragma unroll
            for (int off = 1; off < 16; off <<= 1) s += __shfl_xor(s, off);
            lrow[qi][r] = s;
        }
#pragma unroll
    for (int qi = 0; qi < 4; ++qi) {
        const int qlo = ((qi >> 1) ? qbase1 : qbase0) + (qi & 1) * 16;
#pragma unroll
        for (int dj = 0; dj < 4; ++dj)
#pragma unroll
            for (int r = 0; r < 4; ++r) {
                const size_t o = ((size_t)(b * 1024 + qlo + l4 * 4 + r)) * 1024
                               + h * 64 + dj * 16 + l15;
                Og[o] = f2bf(O[qi][dj][r] / lrow[qi][r]);
            }
    }
}

// ---------------- orchestration
extern "C" void kernel_launch(void* const* d_in, const int* in_sizes, int n_in,
                              void* d_out, int out_size, void* d_ws, size_t ws_size,
                              hipStream_t stream)
{
    (void)in_sizes; (void)n_in; (void)out_size; (void)ws_size;
    const int*   idx  = (const int*)  d_in[0];
    const float* tok  = (const float*)d_in[1];
    const float* pos  = (const float*)d_in[2];
    const float* Wq   = (const float*)d_in[3];
    const float* Wk   = (const float*)d_in[4];
    const float* Wv   = (const float*)d_in[5];
    const float* Wo   = (const float*)d_in[6];
    const float* bo   = (const float*)d_in[7];
    const float* ln1g = (const float*)d_in[8];
    const float* ln1b = (const float*)d_in[9];
    const float* ln2g = (const float*)d_in[10];
    const float* ln2b = (const float*)d_in[11];
    const float* W1   = (const float*)d_in[12];
    const float* b1   = (const float*)d_in[13];
    const float* W2   = (const float*)d_in[14];
    const float* b2   = (const float*)d_in[15];
    const float* lnfg = (const float*)d_in[16];
    const float* lnfb = (const float*)d_in[17];
    const float* Wh   = (const float*)d_in[18];
    const float* bh   = (const float*)d_in[19];

    char* p = (char*)d_ws;
    float* x  = (float*)p; p += (size_t)8192 * 1024 * 4;
    u16* h    = (u16*)p;   p += (size_t)8192 * 1024 * 2;
    u16* qkv  = (u16*)p;   p += (size_t)8192 * 3072 * 2;
    u16* ab   = (u16*)p;   p += (size_t)8192 * 1024 * 2;
    u16* fb   = (u16*)p;   p += (size_t)8192 * 4096 * 2;
    u16* wqT  = (u16*)p;   p += (size_t)1024 * 1024 * 2;   // wq/wk/wv contiguous -> [3072][1024]
    u16* wkT  = (u16*)p;   p += (size_t)1024 * 1024 * 2;
    u16* wvT  = (u16*)p;   p += (size_t)1024 * 1024 * 2;
    u16* woT  = (u16*)p;   p += (size_t)1024 * 1024 * 2;
    u16* w1T  = (u16*)p;   p += (size_t)1024 * 4096 * 2;
    u16* w2T  = (u16*)p;   p += (size_t)4096 * 1024 * 2;
    u16* whT  = (u16*)p;   p += (size_t)1024 * 256 * 2;
    (void)wkT; (void)wvT;

    const dim3 tb(32, 8);
    embed_k<<<8192, 256, 0, stream>>>(idx, tok, pos, x);
    for (int l = 0; l < 6; ++l) {
        transpose_all_k<<<12288, tb, 0, stream>>>(
            Wq + (size_t)l * 1048576, Wk + (size_t)l * 1048576,
            Wv + (size_t)l * 1048576, Wo + (size_t)l * 1048576,
            W1 + (size_t)l * 4194304, W2 + (size_t)l * 4194304,
            wqT, woT, w1T, w2T);

        ln_k<<<8192, 256, 0, stream>>>(x, ln1g + l * 1024, ln1b + l * 1024, h);
        gemm_bt<0><<<1536, 256, 0, stream>>>(h, wqT, nullptr, nullptr, qkv, nullptr, 3072, 1024, 24);
        attn_mfma_k<<<dim3(4, 128), 256, 0, stream>>>(qkv, ab);
        gemm_n64<1><<<1024, 256, 0, stream>>>(ab, woT, bo + l * 1024, x, nullptr, 1024, 1024, 16);
        ln_k<<<8192, 256, 0, stream>>>(x, ln2g + l * 1024, ln2b + l * 1024, h);
        gemm_bt<2><<<2048, 256, 0, stream>>>(h, w1T, b1 + l * 4096, nullptr, fb, nullptr, 4096, 1024, 32);
        gemm_n64<1><<<1024, 256, 0, stream>>>(fb, w2T, b2 + l * 1024, x, nullptr, 1024, 4096, 16);
    }
    transpose_k<<<dim3(8, 32), tb, 0, stream>>>(Wh, whT, 1024, 256);
    ln_k<<<8192, 256, 0, stream>>>(x, lnfg, lnfb, h);
    gemm_n64<3><<<256, 256, 0, stream>>>(h, whT, bh, nullptr, (float*)d_out, 256, 1024, 4);
}